// Round 1
// baseline (1502.392 us; speedup 1.0000x reference)
//
#include <hip/hip_runtime.h>
#include <hip/hip_bf16.h>

#define NN 16384
#define GG 2048
#define KNN 16
#define EE (NN*KNN)
#define NL 4

typedef _Float16 f16;
typedef _Float16 half8 __attribute__((ext_vector_type(8)));
typedef _Float16 half4 __attribute__((ext_vector_type(4)));
typedef float f32x4 __attribute__((ext_vector_type(4)));

__device__ __forceinline__ float gelu_tanh(float x) {
  float x3 = x*x*x;
  float y = 0.7978845608028654f * (x + 0.044715f * x3);
  float e = __expf(2.0f*y);
  float t = 1.0f - 2.0f/(e + 1.0f);
  return 0.5f*x*(1.0f+t);
}

// ---------------- kNN: per node top-16 smallest d2 (matches np f32 bit-exact) ---------
__global__ __launch_bounds__(256) void knn_kernel(const float* __restrict__ pos,
    int* __restrict__ srci, float* __restrict__ dedge) {
  __shared__ float px[GG], py[GG], pz[GG];
  int tid = threadIdx.x;
  int n = blockIdx.x*256 + tid;
  int g = n >> 11;
  int base = g << 11;
  for (int j = tid; j < GG; j += 256) {
    px[j] = pos[(base+j)*3+0];
    py[j] = pos[(base+j)*3+1];
    pz[j] = pos[(base+j)*3+2];
  }
  __syncthreads();
  int li = n & (GG-1);
  float qx = px[li], qy = py[li], qz = pz[li];
  float bd[KNN]; int bi[KNN];
  #pragma unroll
  for (int k = 0; k < KNN; ++k) { bd[k] = 3.4e38f; bi[k] = 0; }
  for (int j = 0; j < GG; ++j) {
    float dx = __fsub_rn(qx, px[j]);
    float dy = __fsub_rn(qy, py[j]);
    float dz = __fsub_rn(qz, pz[j]);
    float d2 = __fadd_rn(__fadd_rn(__fmul_rn(dx,dx), __fmul_rn(dy,dy)), __fmul_rn(dz,dz));
    if (d2 < bd[KNN-1]) {           // strict < : ties keep lower index (matches top_k)
      float cv = d2; int ci = j;
      #pragma unroll
      for (int k = 0; k < KNN; ++k) {   // branch-free sorted bubble insert, static idx
        bool sw = cv < bd[k];
        float ov = bd[k]; int oi = bi[k];
        bd[k] = sw ? cv : ov; bi[k] = sw ? ci : oi;
        cv = sw ? ov : cv;    ci = sw ? oi : ci;
      }
    }
  }
  #pragma unroll
  for (int k = 0; k < KNN; ++k) {
    srci[n*KNN+k] = base + bi[k];
    dedge[n*KNN+k] = sqrtf(bd[k] + 1e-12f);
  }
}

// ---------------- weight transpose + f16 convert (B-operand layout: [col][k]) --------
__global__ __launch_bounds__(256) void prep_kernel(
    const float* __restrict__ Wb2, const float* __restrict__ Wk,
    const float* __restrict__ W1, const float* __restrict__ W2,
    f16* __restrict__ Wb2t, f16* __restrict__ Wkt,
    f16* __restrict__ W1t, f16* __restrict__ W2t) {
  int i = blockIdx.x*256 + threadIdx.x;
  if (i < 16384) {
    int c = i >> 7, k = i & 127;
    Wb2t[i] = (f16)Wb2[k*128 + c];
    return;
  }
  i -= 16384;
  if (i < 65536) {
    int l = i >> 14, r = i & 16383; int c = r >> 7, k = r & 127;
    Wkt[i] = (f16)Wk[l*16384 + k*128 + c];
    return;
  }
  i -= 65536;
  if (i < 262144) {
    int l = i >> 16, r = i & 65535; int c = r >> 7, k = r & 127;   // c<512,k<128
    W1t[i] = (f16)W1[l*65536 + k*512 + c];
    return;
  }
  i -= 262144;
  if (i < 262144) {
    int l = i >> 16, r = i & 65535; int c = r >> 9, k = r & 511;   // c<128,k<512
    W2t[i] = (f16)W2[l*65536 + k*128 + c];
  }
}

// ---------------- embed: h = x[N,65] @ We[65,128] (f32 VALU) -------------------------
__global__ __launch_bounds__(256) void embed_kernel(const float* __restrict__ x,
    const float* __restrict__ We, float* __restrict__ h) {
  int t = threadIdx.x;
  int n = blockIdx.x*8 + (t >> 5);
  int q = (t & 31) * 4;
  f32x4 acc = {0.f,0.f,0.f,0.f};
  const float* xr = x + n*65;
  for (int k = 0; k < 65; ++k) {
    float xv = xr[k];
    f32x4 wv = *(const f32x4*)(We + k*128 + q);
    acc += xv * wv;
  }
  *(f32x4*)(h + (size_t)n*128 + q) = acc;
}

// ---------------- edge basis: kern[E,128] = gelu(gelu(poly@Wb1+bb1)@Wb2+bb2) ---------
__global__ __launch_bounds__(256) void basis_kernel(const float* __restrict__ dedge,
    const float* __restrict__ Wb1, const float* __restrict__ bb1,
    const f16* __restrict__ Wb2t, const float* __restrict__ bb2,
    f16* __restrict__ kern) {
  __shared__ f16 kb[64][136];   // +8 pad: row stride 272B -> bank-safe
  int t = threadIdx.x;
  int e0 = blockIdx.x * 64;
  #pragma unroll
  for (int it = 0; it < 32; ++it) {
    int item = it*256 + t;
    int el = item >> 7;
    int c = item & 127;
    float d = dedge[e0 + el];
    float d2 = d*d, d3 = d2*d;
    float v = d*Wb1[c] + d2*Wb1[128+c] + d3*Wb1[256+c] + bb1[c];
    kb[el][c] = (f16)gelu_tanh(v);
  }
  __syncthreads();
  int w = t >> 6, l = t & 63;
  int row4 = l >> 4, rlo = l & 15;
  half8 a[4];
  #pragma unroll
  for (int kc = 0; kc < 4; ++kc)
    a[kc] = *(const half8*)&kb[w*16 + rlo][kc*32 + row4*8];
  int erow0 = e0 + w*16;
  #pragma unroll
  for (int nt = 0; nt < 8; ++nt) {
    int col = nt*16 + rlo;
    f32x4 acc = {0.f,0.f,0.f,0.f};
    #pragma unroll
    for (int kc = 0; kc < 4; ++kc) {
      half8 b = *(const half8*)&Wb2t[col*128 + kc*32 + row4*8];
      acc = __builtin_amdgcn_mfma_f32_16x16x32_f16(a[kc], b, acc, 0, 0, 0);
    }
    float bias = bb2[col];
    #pragma unroll
    for (int j = 0; j < 4; ++j) {
      int rr = row4*4 + j;
      kern[(size_t)(erow0 + rr)*128 + col] = (f16)gelu_tanh(acc[j] + bias);
    }
  }
}

// ---------------- conv: agg[n] = sum_k h[src]*(kern@Wk)  (fused GEMM+gather+reduce) --
__global__ __launch_bounds__(256) void conv_kernel(const f16* __restrict__ kern,
    const f16* __restrict__ Wkt_l, const int* __restrict__ srci,
    const float* __restrict__ hin, float* __restrict__ agg) {
  int t = threadIdx.x;
  int w = t >> 6, l = t & 63;
  int row4 = l >> 4, rlo = l & 15;
  half8 bf[8][4];               // all of Wk as B-frags, hoisted (128 VGPR)
  #pragma unroll
  for (int nt = 0; nt < 8; ++nt)
    #pragma unroll
    for (int kc = 0; kc < 4; ++kc)
      bf[nt][kc] = *(const half8*)&Wkt_l[(nt*16 + rlo)*128 + kc*32 + row4*8];
  int node0 = blockIdx.x*64 + w*16;
  for (int m = 0; m < 16; ++m) {
    int node = node0 + m;
    size_t ebase = (size_t)node * 16;     // node's 16 edges are one 16-row M-tile
    half8 a[4];
    #pragma unroll
    for (int kc = 0; kc < 4; ++kc)
      a[kc] = *(const half8*)&kern[(ebase + rlo)*128 + kc*32 + row4*8];
    int sidx[4];
    #pragma unroll
    for (int j = 0; j < 4; ++j)
      sidx[j] = srci[ebase + row4*4 + j];
    #pragma unroll
    for (int nt = 0; nt < 8; ++nt) {
      f32x4 acc = {0.f,0.f,0.f,0.f};
      #pragma unroll
      for (int kc = 0; kc < 4; ++kc)
        acc = __builtin_amdgcn_mfma_f32_16x16x32_f16(a[kc], bf[nt][kc], acc, 0, 0, 0);
      int col = nt*16 + rlo;
      float p = 0.f;
      #pragma unroll
      for (int j = 0; j < 4; ++j)
        p += acc[j] * hin[(size_t)sidx[j]*128 + col];
      p += __shfl_xor(p, 16, 64);
      p += __shfl_xor(p, 32, 64);
      if (l < 16) agg[(size_t)node*128 + col] = p;
    }
  }
}

// ---------------- LN + MLP(128->512->128) + residual, fused per 64-node block -------
__global__ __launch_bounds__(256) void mlp_kernel(const float* __restrict__ agg,
    const float* __restrict__ hin,
    const float* __restrict__ lng, const float* __restrict__ lnb,
    const f16* __restrict__ W1t_l, const float* __restrict__ b1_l,
    const f16* __restrict__ W2t_l, const float* __restrict__ b2_l,
    float* __restrict__ hout) {
  __shared__ f16 zl[64][136];
  __shared__ f16 y1[64][520];
  int t = threadIdx.x;
  int w = t >> 6, l = t & 63;
  int n0 = blockIdx.x * 64;
  {  // LayerNorm: 4 lanes per row
    int rloc = w*16 + (l >> 2);
    int q = l & 3;
    size_t nb = (size_t)(n0 + rloc) * 128;
    f32x4 v[8];
    float s = 0.f;
    #pragma unroll
    for (int jj = 0; jj < 8; ++jj) {
      v[jj] = *(const f32x4*)(agg + nb + q*4 + jj*16);
      s += v[jj][0]+v[jj][1]+v[jj][2]+v[jj][3];
    }
    s += __shfl_xor(s, 1, 64);
    s += __shfl_xor(s, 2, 64);
    float mu = s * (1.f/128.f);
    float s2 = 0.f;
    #pragma unroll
    for (int jj = 0; jj < 8; ++jj) {
      f32x4 d = v[jj] - mu;
      s2 += d[0]*d[0]+d[1]*d[1]+d[2]*d[2]+d[3]*d[3];
    }
    s2 += __shfl_xor(s2, 1, 64);
    s2 += __shfl_xor(s2, 2, 64);
    float inv = rsqrtf(s2*(1.f/128.f) + 1e-5f);
    #pragma unroll
    for (int jj = 0; jj < 8; ++jj) {
      int cb = q*4 + jj*16;
      f32x4 gg = *(const f32x4*)(lng + cb);
      f32x4 bb = *(const f32x4*)(lnb + cb);
      f32x4 zz = (v[jj]-mu)*inv*gg + bb;
      half4 hz = { (f16)zz[0], (f16)zz[1], (f16)zz[2], (f16)zz[3] };
      *(half4*)&zl[rloc][cb] = hz;
    }
  }
  __syncthreads();
  int row4 = l >> 4, rlo = l & 15;
  {  // y1 = gelu(z @ W1 + b1)
    half8 a[4];
    #pragma unroll
    for (int kc = 0; kc < 4; ++kc)
      a[kc] = *(const half8*)&zl[w*16 + rlo][kc*32 + row4*8];
    for (int nt = 0; nt < 32; ++nt) {
      int col = nt*16 + rlo;
      f32x4 acc = {0.f,0.f,0.f,0.f};
      #pragma unroll
      for (int kc = 0; kc < 4; ++kc) {
        half8 b = *(const half8*)&W1t_l[(size_t)col*128 + kc*32 + row4*8];
        acc = __builtin_amdgcn_mfma_f32_16x16x32_f16(a[kc], b, acc, 0, 0, 0);
      }
      float bias = b1_l[col];
      #pragma unroll
      for (int j = 0; j < 4; ++j)
        y1[w*16 + row4*4 + j][col] = (f16)gelu_tanh(acc[j] + bias);
    }
  }
  __syncthreads();
  {  // hout = y1 @ W2 + b2 + hin
    half8 a[16];
    #pragma unroll
    for (int kc = 0; kc < 16; ++kc)
      a[kc] = *(const half8*)&y1[w*16 + rlo][kc*32 + row4*8];
    #pragma unroll
    for (int nt = 0; nt < 8; ++nt) {
      int col = nt*16 + rlo;
      f32x4 acc = {0.f,0.f,0.f,0.f};
      #pragma unroll
      for (int kc = 0; kc < 16; ++kc) {
        half8 b = *(const half8*)&W2t_l[(size_t)col*512 + kc*32 + row4*8];
        acc = __builtin_amdgcn_mfma_f32_16x16x32_f16(a[kc], b, acc, 0, 0, 0);
      }
      float bias = b2_l[col];
      #pragma unroll
      for (int j = 0; j < 4; ++j) {
        size_t n = (size_t)(n0 + w*16 + row4*4 + j);
        hout[n*128 + col] = acc[j] + bias + hin[n*128 + col];
      }
    }
  }
}

// ---------------- readout ------------------------------------------------------------
__global__ __launch_bounds__(256) void readout_kernel(const float* __restrict__ h,
    const float* __restrict__ Wr, const float* __restrict__ br, float* __restrict__ out) {
  int n = blockIdx.x*256 + threadIdx.x;
  f32x4 acc = {0.f,0.f,0.f,0.f};
  #pragma unroll
  for (int cb = 0; cb < 32; ++cb) {
    f32x4 hv = *(const f32x4*)(h + (size_t)n*128 + cb*4);
    f32x4 wv = *(const f32x4*)(Wr + cb*4);
    acc += hv*wv;
  }
  out[n] = acc[0]+acc[1]+acc[2]+acc[3] + br[0];
}

extern "C" void kernel_launch(void* const* d_in, const int* in_sizes, int n_in,
                              void* d_out, int out_size, void* d_ws, size_t ws_size,
                              hipStream_t stream) {
  const float* x   = (const float*)d_in[0];
  const float* pos = (const float*)d_in[1];
  const float* We  = (const float*)d_in[3];
  const float* Wb1 = (const float*)d_in[4];
  const float* bb1 = (const float*)d_in[5];
  const float* Wb2 = (const float*)d_in[6];
  const float* bb2 = (const float*)d_in[7];
  const float* Wk  = (const float*)d_in[8];
  const float* lng = (const float*)d_in[9];
  const float* lnb = (const float*)d_in[10];
  const float* W1  = (const float*)d_in[11];
  const float* b1  = (const float*)d_in[12];
  const float* W2  = (const float*)d_in[13];
  const float* b2  = (const float*)d_in[14];
  const float* Wr  = (const float*)d_in[15];
  const float* br  = (const float*)d_in[16];
  float* out = (float*)d_out;

  char* p = (char*)d_ws;
  int*   srci  = (int*)p;     p += (size_t)EE*4;
  float* dedge = (float*)p;   p += (size_t)EE*4;
  f16*   kern  = (f16*)p;     p += (size_t)EE*128*2;
  float* hA    = (float*)p;   p += (size_t)NN*128*4;
  float* hB    = (float*)p;   p += (size_t)NN*128*4;
  float* agg   = (float*)p;   p += (size_t)NN*128*4;
  f16* Wb2t    = (f16*)p;     p += (size_t)16384*2;
  f16* Wkt     = (f16*)p;     p += (size_t)65536*2;
  f16* W1t     = (f16*)p;     p += (size_t)262144*2;
  f16* W2t     = (f16*)p;     p += (size_t)262144*2;

  prep_kernel<<<2368, 256, 0, stream>>>(Wb2, Wk, W1, W2, Wb2t, Wkt, W1t, W2t);
  knn_kernel<<<NN/256, 256, 0, stream>>>(pos, srci, dedge);
  basis_kernel<<<EE/64, 256, 0, stream>>>(dedge, Wb1, bb1, Wb2t, bb2, kern);
  embed_kernel<<<NN/8, 256, 0, stream>>>(x, We, hA);
  float* hin = hA;
  for (int lyr = 0; lyr < NL; ++lyr) {
    float* hout = (hin == hA) ? hB : hA;
    conv_kernel<<<NN/64, 256, 0, stream>>>(kern, Wkt + lyr*16384, srci, hin, agg);
    mlp_kernel<<<NN/64, 256, 0, stream>>>(agg, hin, lng + lyr*128, lnb + lyr*128,
        W1t + (size_t)lyr*65536, b1 + lyr*512, W2t + (size_t)lyr*65536, b2 + lyr*128, hout);
    hin = hout;
  }
  readout_kernel<<<NN/256, 256, 0, stream>>>(hin, Wr, br, out);
}

// Round 2
// 672.771 us; speedup vs baseline: 2.2331x; 2.2331x over previous
//
#include <hip/hip_runtime.h>
#include <hip/hip_bf16.h>

#define NN 16384
#define GG 2048
#define KNN 16
#define EE (NN*KNN)
#define NL 4

typedef _Float16 f16;
typedef _Float16 half8 __attribute__((ext_vector_type(8)));
typedef _Float16 half4 __attribute__((ext_vector_type(4)));
typedef float f32x4 __attribute__((ext_vector_type(4)));
typedef unsigned long long u64;

__device__ __forceinline__ float gelu_tanh(float x) {
  float x3 = x*x*x;
  float y = 0.7978845608028654f * (x + 0.044715f * x3);
  float e = __expf(2.0f*y);
  float t = 1.0f - 2.0f/(e + 1.0f);
  return 0.5f*x*(1.0f+t);
}

// ---------------- kNN: one WAVE per node; per-lane sorted top-16 in named u64 regs ---
// key = (f32bits(d2) << 32) | j  : u64 order == (d2 asc, index asc) == lax.top_k order.
#define INS(kk) { bool sw = key < kk; u64 tmp = kk; kk = sw ? key : kk; key = sw ? tmp : key; }

__global__ __launch_bounds__(256) void knn_kernel(const float* __restrict__ pos,
    int* __restrict__ srci, float* __restrict__ dedge) {
  __shared__ float px[GG], py[GG], pz[GG];
  int tid = threadIdx.x;
  int node = blockIdx.x*4 + (tid >> 6);
  int lane = tid & 63;
  int base = (node >> 11) << 11;
  for (int j = tid; j < GG; j += 256) {
    px[j] = pos[(base+j)*3+0];
    py[j] = pos[(base+j)*3+1];
    pz[j] = pos[(base+j)*3+2];
  }
  __syncthreads();
  int li = node & (GG-1);
  float qx = px[li], qy = py[li], qz = pz[li];
  u64 k0=~0ull,k1=~0ull,k2=~0ull,k3=~0ull,k4=~0ull,k5=~0ull,k6=~0ull,k7=~0ull,
      k8=~0ull,k9=~0ull,k10=~0ull,k11=~0ull,k12=~0ull,k13=~0ull,k14=~0ull,k15=~0ull;
  for (int it = 0; it < 32; ++it) {
    int j = it*64 + lane;
    float dx = __fsub_rn(qx, px[j]);
    float dy = __fsub_rn(qy, py[j]);
    float dz = __fsub_rn(qz, pz[j]);
    float d2 = __fadd_rn(__fadd_rn(__fmul_rn(dx,dx), __fmul_rn(dy,dy)), __fmul_rn(dz,dz));
    u64 key = ((u64)__float_as_uint(d2) << 32) | (unsigned)j;
    if (key < k15) {
      INS(k0) INS(k1) INS(k2) INS(k3) INS(k4) INS(k5) INS(k6) INS(k7)
      INS(k8) INS(k9) INS(k10) INS(k11) INS(k12) INS(k13) INS(k14) INS(k15)
    }
  }
  // merge: 16 rounds of wave-wide u64 min + pop winner's head (keys are unique)
  u64 res = 0;
  for (int r = 0; r < 16; ++r) {
    u64 cur = k0;
    #pragma unroll
    for (int s = 1; s < 64; s <<= 1) {
      u64 o = __shfl_xor(cur, s, 64);
      cur = (o < cur) ? o : cur;
    }
    bool own = (k0 == cur);
    k0 = own?k1:k0;  k1 = own?k2:k1;  k2 = own?k3:k2;  k3 = own?k4:k3;
    k4 = own?k5:k4;  k5 = own?k6:k5;  k6 = own?k7:k6;  k7 = own?k8:k7;
    k8 = own?k9:k8;  k9 = own?k10:k9; k10= own?k11:k10; k11= own?k12:k11;
    k12= own?k13:k12; k13= own?k14:k13; k14= own?k15:k14; k15= own?~0ull:k15;
    res = (lane == r) ? cur : res;
  }
  if (lane < KNN) {
    int j = (int)(res & 0xffffffffu);
    float d2 = __uint_as_float((unsigned)(res >> 32));
    srci[node*KNN + lane] = base + j;
    dedge[node*KNN + lane] = sqrtf(__fadd_rn(d2, 1e-12f));
  }
}

// ---------------- weight transpose + f16 convert (B-operand layout: [col][k]) --------
__global__ __launch_bounds__(256) void prep_kernel(
    const float* __restrict__ Wb2, const float* __restrict__ Wk,
    const float* __restrict__ W1, const float* __restrict__ W2,
    f16* __restrict__ Wb2t, f16* __restrict__ Wkt,
    f16* __restrict__ W1t, f16* __restrict__ W2t) {
  int i = blockIdx.x*256 + threadIdx.x;
  if (i < 16384) {
    int c = i >> 7, k = i & 127;
    Wb2t[i] = (f16)Wb2[k*128 + c];
    return;
  }
  i -= 16384;
  if (i < 65536) {
    int l = i >> 14, r = i & 16383; int c = r >> 7, k = r & 127;
    Wkt[i] = (f16)Wk[l*16384 + k*128 + c];
    return;
  }
  i -= 65536;
  if (i < 262144) {
    int l = i >> 16, r = i & 65535; int c = r >> 7, k = r & 127;   // c<512,k<128
    W1t[i] = (f16)W1[l*65536 + k*512 + c];
    return;
  }
  i -= 262144;
  if (i < 262144) {
    int l = i >> 16, r = i & 65535; int c = r >> 9, k = r & 511;   // c<128,k<512
    W2t[i] = (f16)W2[l*65536 + k*128 + c];
  }
}

// ---------------- embed: h = x[N,65] @ We[65,128] (f32 VALU) -------------------------
__global__ __launch_bounds__(256) void embed_kernel(const float* __restrict__ x,
    const float* __restrict__ We, float* __restrict__ h) {
  int t = threadIdx.x;
  int n = blockIdx.x*8 + (t >> 5);
  int q = (t & 31) * 4;
  f32x4 acc = {0.f,0.f,0.f,0.f};
  const float* xr = x + n*65;
  for (int k = 0; k < 65; ++k) {
    float xv = xr[k];
    f32x4 wv = *(const f32x4*)(We + k*128 + q);
    acc += xv * wv;
  }
  *(f32x4*)(h + (size_t)n*128 + q) = acc;
}

// ---------------- edge basis: kern[E,128] = gelu(gelu(poly@Wb1+bb1)@Wb2+bb2) ---------
__global__ __launch_bounds__(256) void basis_kernel(const float* __restrict__ dedge,
    const float* __restrict__ Wb1, const float* __restrict__ bb1,
    const f16* __restrict__ Wb2t, const float* __restrict__ bb2,
    f16* __restrict__ kern) {
  __shared__ f16 kb[64][136];   // +8 pad: row stride 272B -> bank-safe
  int t = threadIdx.x;
  int e0 = blockIdx.x * 64;
  #pragma unroll
  for (int it = 0; it < 32; ++it) {
    int item = it*256 + t;
    int el = item >> 7;
    int c = item & 127;
    float d = dedge[e0 + el];
    float d2 = d*d, d3 = d2*d;
    float v = d*Wb1[c] + d2*Wb1[128+c] + d3*Wb1[256+c] + bb1[c];
    kb[el][c] = (f16)gelu_tanh(v);
  }
  __syncthreads();
  int w = t >> 6, l = t & 63;
  int row4 = l >> 4, rlo = l & 15;
  half8 a[4];
  #pragma unroll
  for (int kc = 0; kc < 4; ++kc)
    a[kc] = *(const half8*)&kb[w*16 + rlo][kc*32 + row4*8];
  int erow0 = e0 + w*16;
  #pragma unroll
  for (int nt = 0; nt < 8; ++nt) {
    int col = nt*16 + rlo;
    f32x4 acc = {0.f,0.f,0.f,0.f};
    #pragma unroll
    for (int kc = 0; kc < 4; ++kc) {
      half8 b = *(const half8*)&Wb2t[col*128 + kc*32 + row4*8];
      acc = __builtin_amdgcn_mfma_f32_16x16x32_f16(a[kc], b, acc, 0, 0, 0);
    }
    float bias = bb2[col];
    #pragma unroll
    for (int j = 0; j < 4; ++j) {
      int rr = row4*4 + j;
      kern[(size_t)(erow0 + rr)*128 + col] = (f16)gelu_tanh(acc[j] + bias);
    }
  }
}

// ---------------- conv: agg[n] = sum_k h[src]*(kern@Wk)  (fused GEMM+gather+reduce) --
__global__ __launch_bounds__(256) void conv_kernel(const f16* __restrict__ kern,
    const f16* __restrict__ Wkt_l, const int* __restrict__ srci,
    const float* __restrict__ hin, float* __restrict__ agg) {
  int t = threadIdx.x;
  int w = t >> 6, l = t & 63;
  int row4 = l >> 4, rlo = l & 15;
  half8 bf[8][4];               // all of Wk as B-frags, hoisted (128 VGPR)
  #pragma unroll
  for (int nt = 0; nt < 8; ++nt)
    #pragma unroll
    for (int kc = 0; kc < 4; ++kc)
      bf[nt][kc] = *(const half8*)&Wkt_l[(nt*16 + rlo)*128 + kc*32 + row4*8];
  int node0 = blockIdx.x*64 + w*16;
  for (int m = 0; m < 16; ++m) {
    int node = node0 + m;
    size_t ebase = (size_t)node * 16;     // node's 16 edges are one 16-row M-tile
    half8 a[4];
    #pragma unroll
    for (int kc = 0; kc < 4; ++kc)
      a[kc] = *(const half8*)&kern[(ebase + rlo)*128 + kc*32 + row4*8];
    int sidx[4];
    #pragma unroll
    for (int j = 0; j < 4; ++j)
      sidx[j] = srci[ebase + row4*4 + j];
    #pragma unroll
    for (int nt = 0; nt < 8; ++nt) {
      f32x4 acc = {0.f,0.f,0.f,0.f};
      #pragma unroll
      for (int kc = 0; kc < 4; ++kc)
        acc = __builtin_amdgcn_mfma_f32_16x16x32_f16(a[kc], bf[nt][kc], acc, 0, 0, 0);
      int col = nt*16 + rlo;
      float p = 0.f;
      #pragma unroll
      for (int j = 0; j < 4; ++j)
        p += acc[j] * hin[(size_t)sidx[j]*128 + col];
      p += __shfl_xor(p, 16, 64);
      p += __shfl_xor(p, 32, 64);
      if (l < 16) agg[(size_t)node*128 + col] = p;
    }
  }
}

// ---------------- LN + MLP(128->512->128) + residual, fused per 64-node block -------
__global__ __launch_bounds__(256) void mlp_kernel(const float* __restrict__ agg,
    const float* __restrict__ hin,
    const float* __restrict__ lng, const float* __restrict__ lnb,
    const f16* __restrict__ W1t_l, const float* __restrict__ b1_l,
    const f16* __restrict__ W2t_l, const float* __restrict__ b2_l,
    float* __restrict__ hout) {
  __shared__ f16 zl[64][136];
  __shared__ f16 y1[64][520];
  int t = threadIdx.x;
  int w = t >> 6, l = t & 63;
  int n0 = blockIdx.x * 64;
  {  // LayerNorm: 4 lanes per row
    int rloc = w*16 + (l >> 2);
    int q = l & 3;
    size_t nb = (size_t)(n0 + rloc) * 128;
    f32x4 v[8];
    float s = 0.f;
    #pragma unroll
    for (int jj = 0; jj < 8; ++jj) {
      v[jj] = *(const f32x4*)(agg + nb + q*4 + jj*16);
      s += v[jj][0]+v[jj][1]+v[jj][2]+v[jj][3];
    }
    s += __shfl_xor(s, 1, 64);
    s += __shfl_xor(s, 2, 64);
    float mu = s * (1.f/128.f);
    float s2 = 0.f;
    #pragma unroll
    for (int jj = 0; jj < 8; ++jj) {
      f32x4 d = v[jj] - mu;
      s2 += d[0]*d[0]+d[1]*d[1]+d[2]*d[2]+d[3]*d[3];
    }
    s2 += __shfl_xor(s2, 1, 64);
    s2 += __shfl_xor(s2, 2, 64);
    float inv = rsqrtf(s2*(1.f/128.f) + 1e-5f);
    #pragma unroll
    for (int jj = 0; jj < 8; ++jj) {
      int cb = q*4 + jj*16;
      f32x4 gg = *(const f32x4*)(lng + cb);
      f32x4 bb = *(const f32x4*)(lnb + cb);
      f32x4 zz = (v[jj]-mu)*inv*gg + bb;
      half4 hz = { (f16)zz[0], (f16)zz[1], (f16)zz[2], (f16)zz[3] };
      *(half4*)&zl[rloc][cb] = hz;
    }
  }
  __syncthreads();
  int row4 = l >> 4, rlo = l & 15;
  {  // y1 = gelu(z @ W1 + b1)
    half8 a[4];
    #pragma unroll
    for (int kc = 0; kc < 4; ++kc)
      a[kc] = *(const half8*)&zl[w*16 + rlo][kc*32 + row4*8];
    for (int nt = 0; nt < 32; ++nt) {
      int col = nt*16 + rlo;
      f32x4 acc = {0.f,0.f,0.f,0.f};
      #pragma unroll
      for (int kc = 0; kc < 4; ++kc) {
        half8 b = *(const half8*)&W1t_l[(size_t)col*128 + kc*32 + row4*8];
        acc = __builtin_amdgcn_mfma_f32_16x16x32_f16(a[kc], b, acc, 0, 0, 0);
      }
      float bias = b1_l[col];
      #pragma unroll
      for (int j = 0; j < 4; ++j)
        y1[w*16 + row4*4 + j][col] = (f16)gelu_tanh(acc[j] + bias);
    }
  }
  __syncthreads();
  {  // hout = y1 @ W2 + b2 + hin
    half8 a[16];
    #pragma unroll
    for (int kc = 0; kc < 16; ++kc)
      a[kc] = *(const half8*)&y1[w*16 + rlo][kc*32 + row4*8];
    #pragma unroll
    for (int nt = 0; nt < 8; ++nt) {
      int col = nt*16 + rlo;
      f32x4 acc = {0.f,0.f,0.f,0.f};
      #pragma unroll
      for (int kc = 0; kc < 16; ++kc) {
        half8 b = *(const half8*)&W2t_l[(size_t)col*512 + kc*32 + row4*8];
        acc = __builtin_amdgcn_mfma_f32_16x16x32_f16(a[kc], b, acc, 0, 0, 0);
      }
      float bias = b2_l[col];
      #pragma unroll
      for (int j = 0; j < 4; ++j) {
        size_t n = (size_t)(n0 + w*16 + row4*4 + j);
        hout[n*128 + col] = acc[j] + bias + hin[n*128 + col];
      }
    }
  }
}

// ---------------- readout ------------------------------------------------------------
__global__ __launch_bounds__(256) void readout_kernel(const float* __restrict__ h,
    const float* __restrict__ Wr, const float* __restrict__ br, float* __restrict__ out) {
  int n = blockIdx.x*256 + threadIdx.x;
  f32x4 acc = {0.f,0.f,0.f,0.f};
  #pragma unroll
  for (int cb = 0; cb < 32; ++cb) {
    f32x4 hv = *(const f32x4*)(h + (size_t)n*128 + cb*4);
    f32x4 wv = *(const f32x4*)(Wr + cb*4);
    acc += hv*wv;
  }
  out[n] = acc[0]+acc[1]+acc[2]+acc[3] + br[0];
}

extern "C" void kernel_launch(void* const* d_in, const int* in_sizes, int n_in,
                              void* d_out, int out_size, void* d_ws, size_t ws_size,
                              hipStream_t stream) {
  const float* x   = (const float*)d_in[0];
  const float* pos = (const float*)d_in[1];
  const float* We  = (const float*)d_in[3];
  const float* Wb1 = (const float*)d_in[4];
  const float* bb1 = (const float*)d_in[5];
  const float* Wb2 = (const float*)d_in[6];
  const float* bb2 = (const float*)d_in[7];
  const float* Wk  = (const float*)d_in[8];
  const float* lng = (const float*)d_in[9];
  const float* lnb = (const float*)d_in[10];
  const float* W1  = (const float*)d_in[11];
  const float* b1  = (const float*)d_in[12];
  const float* W2  = (const float*)d_in[13];
  const float* b2  = (const float*)d_in[14];
  const float* Wr  = (const float*)d_in[15];
  const float* br  = (const float*)d_in[16];
  float* out = (float*)d_out;

  char* p = (char*)d_ws;
  int*   srci  = (int*)p;     p += (size_t)EE*4;
  float* dedge = (float*)p;   p += (size_t)EE*4;
  f16*   kern  = (f16*)p;     p += (size_t)EE*128*2;
  float* hA    = (float*)p;   p += (size_t)NN*128*4;
  float* hB    = (float*)p;   p += (size_t)NN*128*4;
  float* agg   = (float*)p;   p += (size_t)NN*128*4;
  f16* Wb2t    = (f16*)p;     p += (size_t)16384*2;
  f16* Wkt     = (f16*)p;     p += (size_t)65536*2;
  f16* W1t     = (f16*)p;     p += (size_t)262144*2;
  f16* W2t     = (f16*)p;     p += (size_t)262144*2;

  prep_kernel<<<2368, 256, 0, stream>>>(Wb2, Wk, W1, W2, Wb2t, Wkt, W1t, W2t);
  knn_kernel<<<NN/4, 256, 0, stream>>>(pos, srci, dedge);
  basis_kernel<<<EE/64, 256, 0, stream>>>(dedge, Wb1, bb1, Wb2t, bb2, kern);
  embed_kernel<<<NN/8, 256, 0, stream>>>(x, We, hA);
  float* hin = hA;
  for (int lyr = 0; lyr < NL; ++lyr) {
    float* hout = (hin == hA) ? hB : hA;
    conv_kernel<<<NN/64, 256, 0, stream>>>(kern, Wkt + lyr*16384, srci, hin, agg);
    mlp_kernel<<<NN/64, 256, 0, stream>>>(agg, hin, lng + lyr*128, lnb + lyr*128,
        W1t + (size_t)lyr*65536, b1 + lyr*512, W2t + (size_t)lyr*65536, b2 + lyr*128, hout);
    hin = hout;
  }
  readout_kernel<<<NN/256, 256, 0, stream>>>(hin, Wr, br, out);
}

// Round 3
// 572.121 us; speedup vs baseline: 2.6260x; 1.1759x over previous
//
#include <hip/hip_runtime.h>
#include <hip/hip_bf16.h>

#define NN 16384
#define GG 2048
#define KNN 16
#define EE (NN*KNN)
#define NL 4

typedef _Float16 f16;
typedef _Float16 half8 __attribute__((ext_vector_type(8)));
typedef _Float16 half4 __attribute__((ext_vector_type(4)));
typedef float f32x4 __attribute__((ext_vector_type(4)));
typedef unsigned long long u64;

__device__ __forceinline__ float gelu_tanh(float x) {
  float x3 = x*x*x;
  float y = 0.7978845608028654f * (x + 0.044715f * x3);
  float e = __expf(2.0f*y);
  float t = 1.0f - 2.0f/(e + 1.0f);
  return 0.5f*x*(1.0f+t);
}

// ---------------- kNN: one WAVE per node -------------------------------------------
// key = (f32bits(d2) << 32) | j : u64 order == (d2 asc, idx asc) == lax.top_k order.
// Fast path: 6-deep per-lane sorted list (global top-16 spreads ~uniform over 64
// lanes; P(one lane holds >6 of them) ~ 7.5e-6). Merge counts pops per lane; if any
// lane drains all 6, whole wave redoes the exact 16-deep path (deterministic).
#define INS(kk) { bool sw = key < kk; u64 tmp = kk; kk = sw ? key : kk; key = sw ? tmp : key; }

__global__ __launch_bounds__(256) void knn_kernel(const float* __restrict__ pos,
    int* __restrict__ srci, float* __restrict__ dedge) {
  __shared__ float px[GG], py[GG], pz[GG];
  int tid = threadIdx.x;
  int node = blockIdx.x*4 + (tid >> 6);
  int lane = tid & 63;
  int base = (node >> 11) << 11;
  for (int j = tid; j < GG; j += 256) {
    px[j] = pos[(base+j)*3+0];
    py[j] = pos[(base+j)*3+1];
    pz[j] = pos[(base+j)*3+2];
  }
  __syncthreads();
  int li = node & (GG-1);
  float qx = px[li], qy = py[li], qz = pz[li];

  u64 c0=~0ull,c1=~0ull,c2=~0ull,c3=~0ull,c4=~0ull,c5=~0ull;
  for (int it = 0; it < 32; ++it) {
    int j = it*64 + lane;
    float dx = __fsub_rn(qx, px[j]);
    float dy = __fsub_rn(qy, py[j]);
    float dz = __fsub_rn(qz, pz[j]);
    float d2 = __fadd_rn(__fadd_rn(__fmul_rn(dx,dx), __fmul_rn(dy,dy)), __fmul_rn(dz,dz));
    u64 key = ((u64)__float_as_uint(d2) << 32) | (unsigned)j;
    INS(c0) INS(c1) INS(c2) INS(c3) INS(c4) INS(c5)
  }
  // merge: 16 rounds of wave-wide u64 min + pop winner's head (keys unique)
  u64 res = 0;
  int pc = 0;
  for (int r = 0; r < 16; ++r) {
    u64 cur = c0;
    #pragma unroll
    for (int s = 1; s < 64; s <<= 1) {
      u64 o = __shfl_xor(cur, s, 64);
      cur = (o < cur) ? o : cur;
    }
    bool own = (c0 == cur);
    pc += own ? 1 : 0;
    c0 = own?c1:c0; c1 = own?c2:c1; c2 = own?c3:c2;
    c3 = own?c4:c3; c4 = own?c5:c4; c5 = own?~0ull:c5;
    res = (lane == r) ? cur : res;
  }
  if (__any(pc >= 6)) {
    // exact fallback: 16-deep per-lane list (rare: ~1e-5 of nodes)
    u64 k0=~0ull,k1=~0ull,k2=~0ull,k3=~0ull,k4=~0ull,k5=~0ull,k6=~0ull,k7=~0ull,
        k8=~0ull,k9=~0ull,k10=~0ull,k11=~0ull,k12=~0ull,k13=~0ull,k14=~0ull,k15=~0ull;
    for (int it = 0; it < 32; ++it) {
      int j = it*64 + lane;
      float dx = __fsub_rn(qx, px[j]);
      float dy = __fsub_rn(qy, py[j]);
      float dz = __fsub_rn(qz, pz[j]);
      float d2 = __fadd_rn(__fadd_rn(__fmul_rn(dx,dx), __fmul_rn(dy,dy)), __fmul_rn(dz,dz));
      u64 key = ((u64)__float_as_uint(d2) << 32) | (unsigned)j;
      if (key < k15) {
        INS(k0) INS(k1) INS(k2) INS(k3) INS(k4) INS(k5) INS(k6) INS(k7)
        INS(k8) INS(k9) INS(k10) INS(k11) INS(k12) INS(k13) INS(k14) INS(k15)
      }
    }
    res = 0;
    for (int r = 0; r < 16; ++r) {
      u64 cur = k0;
      #pragma unroll
      for (int s = 1; s < 64; s <<= 1) {
        u64 o = __shfl_xor(cur, s, 64);
        cur = (o < cur) ? o : cur;
      }
      bool own = (k0 == cur);
      k0 = own?k1:k0;  k1 = own?k2:k1;  k2 = own?k3:k2;  k3 = own?k4:k3;
      k4 = own?k5:k4;  k5 = own?k6:k5;  k6 = own?k7:k6;  k7 = own?k8:k7;
      k8 = own?k9:k8;  k9 = own?k10:k9; k10= own?k11:k10; k11= own?k12:k11;
      k12= own?k13:k12; k13= own?k14:k13; k14= own?k15:k14; k15= own?~0ull:k15;
      res = (lane == r) ? cur : res;
    }
  }
  if (lane < KNN) {
    int j = (int)(res & 0xffffffffu);
    float d2 = __uint_as_float((unsigned)(res >> 32));
    srci[node*KNN + lane] = base + j;
    dedge[node*KNN + lane] = sqrtf(__fadd_rn(d2, 1e-12f));
  }
}

// ---------------- weight transpose + f16 convert (B-operand layout: [col][k]) --------
__global__ __launch_bounds__(256) void prep_kernel(
    const float* __restrict__ Wb2, const float* __restrict__ Wk,
    const float* __restrict__ W1, const float* __restrict__ W2,
    f16* __restrict__ Wb2t, f16* __restrict__ Wkt,
    f16* __restrict__ W1t, f16* __restrict__ W2t) {
  int i = blockIdx.x*256 + threadIdx.x;
  if (i < 16384) {
    int c = i >> 7, k = i & 127;
    Wb2t[i] = (f16)Wb2[k*128 + c];
    return;
  }
  i -= 16384;
  if (i < 65536) {
    int l = i >> 14, r = i & 16383; int c = r >> 7, k = r & 127;
    Wkt[i] = (f16)Wk[l*16384 + k*128 + c];
    return;
  }
  i -= 65536;
  if (i < 262144) {
    int l = i >> 16, r = i & 65535; int c = r >> 7, k = r & 127;   // c<512,k<128
    W1t[i] = (f16)W1[l*65536 + k*512 + c];
    return;
  }
  i -= 262144;
  if (i < 262144) {
    int l = i >> 16, r = i & 65535; int c = r >> 9, k = r & 511;   // c<128,k<512
    W2t[i] = (f16)W2[l*65536 + k*128 + c];
  }
}

// ---------------- embed: h = x[N,65] @ We[65,128] (f32 VALU) -------------------------
__global__ __launch_bounds__(256) void embed_kernel(const float* __restrict__ x,
    const float* __restrict__ We, float* __restrict__ h) {
  int t = threadIdx.x;
  int n = blockIdx.x*8 + (t >> 5);
  int q = (t & 31) * 4;
  f32x4 acc = {0.f,0.f,0.f,0.f};
  const float* xr = x + n*65;
  for (int k = 0; k < 65; ++k) {
    float xv = xr[k];
    f32x4 wv = *(const f32x4*)(We + k*128 + q);
    acc += xv * wv;
  }
  *(f32x4*)(h + (size_t)n*128 + q) = acc;
}

// ---------------- edge basis: kern[E,128] = gelu(gelu(poly@Wb1+bb1)@Wb2+bb2) ---------
__global__ __launch_bounds__(256) void basis_kernel(const float* __restrict__ dedge,
    const float* __restrict__ Wb1, const float* __restrict__ bb1,
    const f16* __restrict__ Wb2t, const float* __restrict__ bb2,
    f16* __restrict__ kern) {
  __shared__ f16 kb[64][136];   // +8 pad: row stride 272B -> bank-safe
  int t = threadIdx.x;
  int e0 = blockIdx.x * 64;
  #pragma unroll
  for (int it = 0; it < 32; ++it) {
    int item = it*256 + t;
    int el = item >> 7;
    int c = item & 127;
    float d = dedge[e0 + el];
    float d2 = d*d, d3 = d2*d;
    float v = d*Wb1[c] + d2*Wb1[128+c] + d3*Wb1[256+c] + bb1[c];
    kb[el][c] = (f16)gelu_tanh(v);
  }
  __syncthreads();
  int w = t >> 6, l = t & 63;
  int row4 = l >> 4, rlo = l & 15;
  half8 a[4];
  #pragma unroll
  for (int kc = 0; kc < 4; ++kc)
    a[kc] = *(const half8*)&kb[w*16 + rlo][kc*32 + row4*8];
  int erow0 = e0 + w*16;
  #pragma unroll
  for (int nt = 0; nt < 8; ++nt) {
    int col = nt*16 + rlo;
    f32x4 acc = {0.f,0.f,0.f,0.f};
    #pragma unroll
    for (int kc = 0; kc < 4; ++kc) {
      half8 b = *(const half8*)&Wb2t[col*128 + kc*32 + row4*8];
      acc = __builtin_amdgcn_mfma_f32_16x16x32_f16(a[kc], b, acc, 0, 0, 0);
    }
    float bias = bb2[col];
    #pragma unroll
    for (int j = 0; j < 4; ++j) {
      int rr = row4*4 + j;
      kern[(size_t)(erow0 + rr)*128 + col] = (f16)gelu_tanh(acc[j] + bias);
    }
  }
}

// ---------------- conv: agg[n] = sum_k h[src]*(kern@Wk)  (fused GEMM+gather+reduce) --
__global__ __launch_bounds__(256) void conv_kernel(const f16* __restrict__ kern,
    const f16* __restrict__ Wkt_l, const int* __restrict__ srci,
    const float* __restrict__ hin, float* __restrict__ agg) {
  int t = threadIdx.x;
  int w = t >> 6, l = t & 63;
  int row4 = l >> 4, rlo = l & 15;
  half8 bf[8][4];               // all of Wk as B-frags, hoisted (128 VGPR)
  #pragma unroll
  for (int nt = 0; nt < 8; ++nt)
    #pragma unroll
    for (int kc = 0; kc < 4; ++kc)
      bf[nt][kc] = *(const half8*)&Wkt_l[(nt*16 + rlo)*128 + kc*32 + row4*8];
  int node0 = blockIdx.x*64 + w*16;
  for (int m = 0; m < 16; ++m) {
    int node = node0 + m;
    size_t ebase = (size_t)node * 16;     // node's 16 edges are one 16-row M-tile
    half8 a[4];
    #pragma unroll
    for (int kc = 0; kc < 4; ++kc)
      a[kc] = *(const half8*)&kern[(ebase + rlo)*128 + kc*32 + row4*8];
    int sidx[4];
    #pragma unroll
    for (int j = 0; j < 4; ++j)
      sidx[j] = srci[ebase + row4*4 + j];
    #pragma unroll
    for (int nt = 0; nt < 8; ++nt) {
      f32x4 acc = {0.f,0.f,0.f,0.f};
      #pragma unroll
      for (int kc = 0; kc < 4; ++kc)
        acc = __builtin_amdgcn_mfma_f32_16x16x32_f16(a[kc], bf[nt][kc], acc, 0, 0, 0);
      int col = nt*16 + rlo;
      float p = 0.f;
      #pragma unroll
      for (int j = 0; j < 4; ++j)
        p += acc[j] * hin[(size_t)sidx[j]*128 + col];
      p += __shfl_xor(p, 16, 64);
      p += __shfl_xor(p, 32, 64);
      if (l < 16) agg[(size_t)node*128 + col] = p;
    }
  }
}

// ---------------- LN + MLP(128->512->128) + residual, fused per 64-node block -------
__global__ __launch_bounds__(256) void mlp_kernel(const float* __restrict__ agg,
    const float* __restrict__ hin,
    const float* __restrict__ lng, const float* __restrict__ lnb,
    const f16* __restrict__ W1t_l, const float* __restrict__ b1_l,
    const f16* __restrict__ W2t_l, const float* __restrict__ b2_l,
    float* __restrict__ hout) {
  __shared__ f16 zl[64][136];
  __shared__ f16 y1[64][520];
  int t = threadIdx.x;
  int w = t >> 6, l = t & 63;
  int n0 = blockIdx.x * 64;
  {  // LayerNorm: 4 lanes per row
    int rloc = w*16 + (l >> 2);
    int q = l & 3;
    size_t nb = (size_t)(n0 + rloc) * 128;
    f32x4 v[8];
    float s = 0.f;
    #pragma unroll
    for (int jj = 0; jj < 8; ++jj) {
      v[jj] = *(const f32x4*)(agg + nb + q*4 + jj*16);
      s += v[jj][0]+v[jj][1]+v[jj][2]+v[jj][3];
    }
    s += __shfl_xor(s, 1, 64);
    s += __shfl_xor(s, 2, 64);
    float mu = s * (1.f/128.f);
    float s2 = 0.f;
    #pragma unroll
    for (int jj = 0; jj < 8; ++jj) {
      f32x4 d = v[jj] - mu;
      s2 += d[0]*d[0]+d[1]*d[1]+d[2]*d[2]+d[3]*d[3];
    }
    s2 += __shfl_xor(s2, 1, 64);
    s2 += __shfl_xor(s2, 2, 64);
    float inv = rsqrtf(s2*(1.f/128.f) + 1e-5f);
    #pragma unroll
    for (int jj = 0; jj < 8; ++jj) {
      int cb = q*4 + jj*16;
      f32x4 gg = *(const f32x4*)(lng + cb);
      f32x4 bb = *(const f32x4*)(lnb + cb);
      f32x4 zz = (v[jj]-mu)*inv*gg + bb;
      half4 hz = { (f16)zz[0], (f16)zz[1], (f16)zz[2], (f16)zz[3] };
      *(half4*)&zl[rloc][cb] = hz;
    }
  }
  __syncthreads();
  int row4 = l >> 4, rlo = l & 15;
  {  // y1 = gelu(z @ W1 + b1)
    half8 a[4];
    #pragma unroll
    for (int kc = 0; kc < 4; ++kc)
      a[kc] = *(const half8*)&zl[w*16 + rlo][kc*32 + row4*8];
    for (int nt = 0; nt < 32; ++nt) {
      int col = nt*16 + rlo;
      f32x4 acc = {0.f,0.f,0.f,0.f};
      #pragma unroll
      for (int kc = 0; kc < 4; ++kc) {
        half8 b = *(const half8*)&W1t_l[(size_t)col*128 + kc*32 + row4*8];
        acc = __builtin_amdgcn_mfma_f32_16x16x32_f16(a[kc], b, acc, 0, 0, 0);
      }
      float bias = b1_l[col];
      #pragma unroll
      for (int j = 0; j < 4; ++j)
        y1[w*16 + row4*4 + j][col] = (f16)gelu_tanh(acc[j] + bias);
    }
  }
  __syncthreads();
  {  // hout = y1 @ W2 + b2 + hin
    half8 a[16];
    #pragma unroll
    for (int kc = 0; kc < 16; ++kc)
      a[kc] = *(const half8*)&y1[w*16 + rlo][kc*32 + row4*8];
    #pragma unroll
    for (int nt = 0; nt < 8; ++nt) {
      int col = nt*16 + rlo;
      f32x4 acc = {0.f,0.f,0.f,0.f};
      #pragma unroll
      for (int kc = 0; kc < 16; ++kc) {
        half8 b = *(const half8*)&W2t_l[(size_t)col*512 + kc*32 + row4*8];
        acc = __builtin_amdgcn_mfma_f32_16x16x32_f16(a[kc], b, acc, 0, 0, 0);
      }
      float bias = b2_l[col];
      #pragma unroll
      for (int j = 0; j < 4; ++j) {
        size_t n = (size_t)(n0 + w*16 + row4*4 + j);
        hout[n*128 + col] = acc[j] + bias + hin[n*128 + col];
      }
    }
  }
}

// ---------------- readout ------------------------------------------------------------
__global__ __launch_bounds__(256) void readout_kernel(const float* __restrict__ h,
    const float* __restrict__ Wr, const float* __restrict__ br, float* __restrict__ out) {
  int n = blockIdx.x*256 + threadIdx.x;
  f32x4 acc = {0.f,0.f,0.f,0.f};
  #pragma unroll
  for (int cb = 0; cb < 32; ++cb) {
    f32x4 hv = *(const f32x4*)(h + (size_t)n*128 + cb*4);
    f32x4 wv = *(const f32x4*)(Wr + cb*4);
    acc += hv*wv;
  }
  out[n] = acc[0]+acc[1]+acc[2]+acc[3] + br[0];
}

extern "C" void kernel_launch(void* const* d_in, const int* in_sizes, int n_in,
                              void* d_out, int out_size, void* d_ws, size_t ws_size,
                              hipStream_t stream) {
  const float* x   = (const float*)d_in[0];
  const float* pos = (const float*)d_in[1];
  const float* We  = (const float*)d_in[3];
  const float* Wb1 = (const float*)d_in[4];
  const float* bb1 = (const float*)d_in[5];
  const float* Wb2 = (const float*)d_in[6];
  const float* bb2 = (const float*)d_in[7];
  const float* Wk  = (const float*)d_in[8];
  const float* lng = (const float*)d_in[9];
  const float* lnb = (const float*)d_in[10];
  const float* W1  = (const float*)d_in[11];
  const float* b1  = (const float*)d_in[12];
  const float* W2  = (const float*)d_in[13];
  const float* b2  = (const float*)d_in[14];
  const float* Wr  = (const float*)d_in[15];
  const float* br  = (const float*)d_in[16];
  float* out = (float*)d_out;

  char* p = (char*)d_ws;
  int*   srci  = (int*)p;     p += (size_t)EE*4;
  float* dedge = (float*)p;   p += (size_t)EE*4;
  f16*   kern  = (f16*)p;     p += (size_t)EE*128*2;
  float* hA    = (float*)p;   p += (size_t)NN*128*4;
  float* hB    = (float*)p;   p += (size_t)NN*128*4;
  float* agg   = (float*)p;   p += (size_t)NN*128*4;
  f16* Wb2t    = (f16*)p;     p += (size_t)16384*2;
  f16* Wkt     = (f16*)p;     p += (size_t)65536*2;
  f16* W1t     = (f16*)p;     p += (size_t)262144*2;
  f16* W2t     = (f16*)p;     p += (size_t)262144*2;

  prep_kernel<<<2368, 256, 0, stream>>>(Wb2, Wk, W1, W2, Wb2t, Wkt, W1t, W2t);
  knn_kernel<<<NN/4, 256, 0, stream>>>(pos, srci, dedge);
  basis_kernel<<<EE/64, 256, 0, stream>>>(dedge, Wb1, bb1, Wb2t, bb2, kern);
  embed_kernel<<<NN/8, 256, 0, stream>>>(x, We, hA);
  float* hin = hA;
  for (int lyr = 0; lyr < NL; ++lyr) {
    float* hout = (hin == hA) ? hB : hA;
    conv_kernel<<<NN/64, 256, 0, stream>>>(kern, Wkt + lyr*16384, srci, hin, agg);
    mlp_kernel<<<NN/64, 256, 0, stream>>>(agg, hin, lng + lyr*128, lnb + lyr*128,
        W1t + (size_t)lyr*65536, b1 + lyr*512, W2t + (size_t)lyr*65536, b2 + lyr*128, hout);
    hin = hout;
  }
  readout_kernel<<<NN/256, 256, 0, stream>>>(hin, Wr, br, out);
}

// Round 4
// 525.236 us; speedup vs baseline: 2.8604x; 1.0893x over previous
//
#include <hip/hip_runtime.h>
#include <hip/hip_bf16.h>

#define NN 16384
#define GG 2048
#define KNN 16
#define EE (NN*KNN)
#define NL 4

typedef _Float16 f16;
typedef _Float16 half8 __attribute__((ext_vector_type(8)));
typedef _Float16 half4 __attribute__((ext_vector_type(4)));
typedef float f32x4 __attribute__((ext_vector_type(4)));
typedef unsigned long long u64;

// gelu tanh-approx in sigmoid form: x*sigmoid(2y), y=a(x+b x^3), a=0.79788456, b=0.044715
// = x * rcp(1 + exp(x*(-2a - 2ab x^2))).  ~8 VALU ops (v_exp + v_rcp native).
__device__ __forceinline__ float gelu_tanh(float x) {
  float s = x*x;
  float u = __fmaf_rn(-0.0713548194f, s, -1.5957691216f);   // -2ab*s - 2a
  float p = __expf(x*u);
  return x * __builtin_amdgcn_rcpf(1.0f + p);
}

// ---------------- kNN: one WAVE per node -------------------------------------------
// key = (f32bits(d2) << 32) | j : u64 order == (d2 asc, idx asc) == lax.top_k order.
// Fast path: 6-deep per-lane sorted list; exact 16-deep fallback if any lane drains.
#define INS(kk) { bool sw = key < kk; u64 tmp = kk; kk = sw ? key : kk; key = sw ? tmp : key; }

__global__ __launch_bounds__(256) void knn_kernel(const float* __restrict__ pos,
    int* __restrict__ srci, float* __restrict__ dedge) {
  __shared__ float px[GG], py[GG], pz[GG];
  int tid = threadIdx.x;
  int node = blockIdx.x*4 + (tid >> 6);
  int lane = tid & 63;
  int base = (node >> 11) << 11;
  for (int j = tid; j < GG; j += 256) {
    px[j] = pos[(base+j)*3+0];
    py[j] = pos[(base+j)*3+1];
    pz[j] = pos[(base+j)*3+2];
  }
  __syncthreads();
  int li = node & (GG-1);
  float qx = px[li], qy = py[li], qz = pz[li];

  u64 c0=~0ull,c1=~0ull,c2=~0ull,c3=~0ull,c4=~0ull,c5=~0ull;
  for (int it = 0; it < 32; ++it) {
    int j = it*64 + lane;
    float dx = __fsub_rn(qx, px[j]);
    float dy = __fsub_rn(qy, py[j]);
    float dz = __fsub_rn(qz, pz[j]);
    float d2 = __fadd_rn(__fadd_rn(__fmul_rn(dx,dx), __fmul_rn(dy,dy)), __fmul_rn(dz,dz));
    u64 key = ((u64)__float_as_uint(d2) << 32) | (unsigned)j;
    INS(c0) INS(c1) INS(c2) INS(c3) INS(c4) INS(c5)
  }
  u64 res = 0;
  int pc = 0;
  for (int r = 0; r < 16; ++r) {
    u64 cur = c0;
    #pragma unroll
    for (int s = 1; s < 64; s <<= 1) {
      u64 o = __shfl_xor(cur, s, 64);
      cur = (o < cur) ? o : cur;
    }
    bool own = (c0 == cur);
    pc += own ? 1 : 0;
    c0 = own?c1:c0; c1 = own?c2:c1; c2 = own?c3:c2;
    c3 = own?c4:c3; c4 = own?c5:c4; c5 = own?~0ull:c5;
    res = (lane == r) ? cur : res;
  }
  if (__any(pc >= 6)) {
    u64 k0=~0ull,k1=~0ull,k2=~0ull,k3=~0ull,k4=~0ull,k5=~0ull,k6=~0ull,k7=~0ull,
        k8=~0ull,k9=~0ull,k10=~0ull,k11=~0ull,k12=~0ull,k13=~0ull,k14=~0ull,k15=~0ull;
    for (int it = 0; it < 32; ++it) {
      int j = it*64 + lane;
      float dx = __fsub_rn(qx, px[j]);
      float dy = __fsub_rn(qy, py[j]);
      float dz = __fsub_rn(qz, pz[j]);
      float d2 = __fadd_rn(__fadd_rn(__fmul_rn(dx,dx), __fmul_rn(dy,dy)), __fmul_rn(dz,dz));
      u64 key = ((u64)__float_as_uint(d2) << 32) | (unsigned)j;
      if (key < k15) {
        INS(k0) INS(k1) INS(k2) INS(k3) INS(k4) INS(k5) INS(k6) INS(k7)
        INS(k8) INS(k9) INS(k10) INS(k11) INS(k12) INS(k13) INS(k14) INS(k15)
      }
    }
    res = 0;
    for (int r = 0; r < 16; ++r) {
      u64 cur = k0;
      #pragma unroll
      for (int s = 1; s < 64; s <<= 1) {
        u64 o = __shfl_xor(cur, s, 64);
        cur = (o < cur) ? o : cur;
      }
      bool own = (k0 == cur);
      k0 = own?k1:k0;  k1 = own?k2:k1;  k2 = own?k3:k2;  k3 = own?k4:k3;
      k4 = own?k5:k4;  k5 = own?k6:k5;  k6 = own?k7:k6;  k7 = own?k8:k7;
      k8 = own?k9:k8;  k9 = own?k10:k9; k10= own?k11:k10; k11= own?k12:k11;
      k12= own?k13:k12; k13= own?k14:k13; k14= own?k15:k14; k15= own?~0ull:k15;
      res = (lane == r) ? cur : res;
    }
  }
  if (lane < KNN) {
    int j = (int)(res & 0xffffffffu);
    float d2 = __uint_as_float((unsigned)(res >> 32));
    srci[node*KNN + lane] = base + j;
    dedge[node*KNN + lane] = sqrtf(__fadd_rn(d2, 1e-12f));
  }
}

// ---------------- weight transpose + f16 convert (B-operand layout: [col][k]) --------
__global__ __launch_bounds__(256) void prep_kernel(
    const float* __restrict__ Wb2, const float* __restrict__ Wk,
    const float* __restrict__ W1, const float* __restrict__ W2,
    f16* __restrict__ Wb2t, f16* __restrict__ Wkt,
    f16* __restrict__ W1t, f16* __restrict__ W2t) {
  int i = blockIdx.x*256 + threadIdx.x;
  if (i < 16384) {
    int c = i >> 7, k = i & 127;
    Wb2t[i] = (f16)Wb2[k*128 + c];
    return;
  }
  i -= 16384;
  if (i < 65536) {
    int l = i >> 14, r = i & 16383; int c = r >> 7, k = r & 127;
    Wkt[i] = (f16)Wk[l*16384 + k*128 + c];
    return;
  }
  i -= 65536;
  if (i < 262144) {
    int l = i >> 16, r = i & 65535; int c = r >> 7, k = r & 127;   // c<512,k<128
    W1t[i] = (f16)W1[l*65536 + k*512 + c];
    return;
  }
  i -= 262144;
  if (i < 262144) {
    int l = i >> 16, r = i & 65535; int c = r >> 9, k = r & 511;   // c<128,k<512
    W2t[i] = (f16)W2[l*65536 + k*128 + c];
  }
}

// ---------------- embed: h = x[N,65] @ We[65,128] (f32 VALU) -------------------------
__global__ __launch_bounds__(256) void embed_kernel(const float* __restrict__ x,
    const float* __restrict__ We, float* __restrict__ h) {
  int t = threadIdx.x;
  int n = blockIdx.x*8 + (t >> 5);
  int q = (t & 31) * 4;
  f32x4 acc = {0.f,0.f,0.f,0.f};
  const float* xr = x + n*65;
  for (int k = 0; k < 65; ++k) {
    float xv = xr[k];
    f32x4 wv = *(const f32x4*)(We + k*128 + q);
    acc += xv * wv;
  }
  *(f32x4*)(h + (size_t)n*128 + q) = acc;
}

// ---------------- edge basis -> kernA in A-FRAGMENT order ----------------------------
// kernA layout: [tile][kc][lane][8] halves, tile = node = 16-edge group.
// Both the write here and conv's read are fully coalesced 1KB/instr.
__global__ __launch_bounds__(256) void basis_kernel(const float* __restrict__ dedge,
    const float* __restrict__ Wb1, const float* __restrict__ bb1,
    const f16* __restrict__ Wb2t, const float* __restrict__ bb2,
    f16* __restrict__ kernA) {
  __shared__ f16 kb[64][136];   // phase1: kb matrix; phase2: reused for out-tile
  int t = threadIdx.x;
  int e0 = blockIdx.x * 64;
  // phase 1: kb = gelu(poly @ Wb1 + bb1)
  {
    int c = t & 127;
    int rbase = t >> 7;         // 0 or 1
    float w1 = Wb1[c], w2 = Wb1[128+c], w3 = Wb1[256+c], b0 = bb1[c];
    #pragma unroll
    for (int it = 0; it < 32; ++it) {
      int el = it*2 + rbase;
      float d = dedge[e0 + el];
      float d2 = d*d, d3 = d2*d;
      kb[el][c] = (f16)gelu_tanh(d*w1 + d2*w2 + d3*w3 + b0);
    }
  }
  __syncthreads();
  int w = t >> 6, l = t & 63;
  int row4 = l >> 4, rlo = l & 15;
  half8 a[4];
  #pragma unroll
  for (int kc = 0; kc < 4; ++kc)
    a[kc] = *(const half8*)&kb[w*16 + rlo][kc*32 + row4*8];
  f32x4 acc[8];
  #pragma unroll
  for (int nt = 0; nt < 8; ++nt) {
    acc[nt] = (f32x4){0.f,0.f,0.f,0.f};
    #pragma unroll
    for (int kc = 0; kc < 4; ++kc) {
      half8 b = *(const half8*)&Wb2t[(nt*16 + rlo)*128 + kc*32 + row4*8];
      acc[nt] = __builtin_amdgcn_mfma_f32_16x16x32_f16(a[kc], b, acc[nt], 0, 0, 0);
    }
  }
  __syncthreads();              // all kb reads done; safe to overwrite
  #pragma unroll
  for (int nt = 0; nt < 8; ++nt) {
    float bias = bb2[nt*16 + rlo];
    #pragma unroll
    for (int j = 0; j < 4; ++j)
      kb[w*16 + row4*4 + j][nt*16 + rlo] = (f16)gelu_tanh(acc[nt][j] + bias);
  }
  __syncthreads();
  // phase 3: write A-frag order: lane l of tile Tg -> contiguous 16B, 1KB per instr
  size_t Tg = (size_t)blockIdx.x*4 + w;
  #pragma unroll
  for (int kc = 0; kc < 4; ++kc) {
    half8 v = *(const half8*)&kb[w*16 + rlo][kc*32 + row4*8];
    *(half8*)&kernA[((Tg*4 + kc)*64 + l)*8] = v;
  }
}

// ---------------- conv: agg[n] = sum_k h[src]*(kern@Wk)  (fused GEMM+gather+reduce) --
__global__ __launch_bounds__(256) void conv_kernel(const f16* __restrict__ kernA,
    const f16* __restrict__ Wkt_l, const int* __restrict__ srci,
    const float* __restrict__ hin, float* __restrict__ agg) {
  int t = threadIdx.x;
  int w = t >> 6, l = t & 63;
  int row4 = l >> 4, rlo = l & 15;
  half8 bf[8][4];               // all of Wk as B-frags, hoisted (128 VGPR)
  #pragma unroll
  for (int nt = 0; nt < 8; ++nt)
    #pragma unroll
    for (int kc = 0; kc < 4; ++kc)
      bf[nt][kc] = *(const half8*)&Wkt_l[(nt*16 + rlo)*128 + kc*32 + row4*8];
  int node0 = blockIdx.x*64 + w*16;
  for (int m = 0; m < 16; ++m) {
    int node = node0 + m;
    size_t ebase = (size_t)node * 16;     // node's 16 edges are one 16-row M-tile
    half8 a[4];
    #pragma unroll
    for (int kc = 0; kc < 4; ++kc)        // A-frag order: coalesced 1KB loads
      a[kc] = *(const half8*)&kernA[(((size_t)node*4 + kc)*64 + l)*8];
    int sidx[4];
    #pragma unroll
    for (int j = 0; j < 4; ++j)
      sidx[j] = srci[ebase + row4*4 + j];
    #pragma unroll
    for (int nt = 0; nt < 8; ++nt) {
      f32x4 acc = {0.f,0.f,0.f,0.f};
      #pragma unroll
      for (int kc = 0; kc < 4; ++kc)
        acc = __builtin_amdgcn_mfma_f32_16x16x32_f16(a[kc], bf[nt][kc], acc, 0, 0, 0);
      int col = nt*16 + rlo;
      float p = 0.f;
      #pragma unroll
      for (int j = 0; j < 4; ++j)
        p += acc[j] * hin[(size_t)sidx[j]*128 + col];
      p += __shfl_xor(p, 16, 64);
      p += __shfl_xor(p, 32, 64);
      if (l < 16) agg[(size_t)node*128 + col] = p;
    }
  }
}

// ---------------- LN + MLP(128->512->128) + residual, fused per 64-node block -------
__global__ __launch_bounds__(256) void mlp_kernel(const float* __restrict__ agg,
    const float* __restrict__ hin,
    const float* __restrict__ lng, const float* __restrict__ lnb,
    const f16* __restrict__ W1t_l, const float* __restrict__ b1_l,
    const f16* __restrict__ W2t_l, const float* __restrict__ b2_l,
    float* __restrict__ hout) {
  __shared__ f16 zl[64][136];
  __shared__ f16 y1[64][520];
  int t = threadIdx.x;
  int w = t >> 6, l = t & 63;
  int n0 = blockIdx.x * 64;
  {  // LayerNorm: 4 lanes per row
    int rloc = w*16 + (l >> 2);
    int q = l & 3;
    size_t nb = (size_t)(n0 + rloc) * 128;
    f32x4 v[8];
    float s = 0.f;
    #pragma unroll
    for (int jj = 0; jj < 8; ++jj) {
      v[jj] = *(const f32x4*)(agg + nb + q*4 + jj*16);
      s += v[jj][0]+v[jj][1]+v[jj][2]+v[jj][3];
    }
    s += __shfl_xor(s, 1, 64);
    s += __shfl_xor(s, 2, 64);
    float mu = s * (1.f/128.f);
    float s2 = 0.f;
    #pragma unroll
    for (int jj = 0; jj < 8; ++jj) {
      f32x4 d = v[jj] - mu;
      s2 += d[0]*d[0]+d[1]*d[1]+d[2]*d[2]+d[3]*d[3];
    }
    s2 += __shfl_xor(s2, 1, 64);
    s2 += __shfl_xor(s2, 2, 64);
    float inv = rsqrtf(s2*(1.f/128.f) + 1e-5f);
    #pragma unroll
    for (int jj = 0; jj < 8; ++jj) {
      int cb = q*4 + jj*16;
      f32x4 gg = *(const f32x4*)(lng + cb);
      f32x4 bb = *(const f32x4*)(lnb + cb);
      f32x4 zz = (v[jj]-mu)*inv*gg + bb;
      half4 hz = { (f16)zz[0], (f16)zz[1], (f16)zz[2], (f16)zz[3] };
      *(half4*)&zl[rloc][cb] = hz;
    }
  }
  __syncthreads();
  int row4 = l >> 4, rlo = l & 15;
  {  // y1 = gelu(z @ W1 + b1)
    half8 a[4];
    #pragma unroll
    for (int kc = 0; kc < 4; ++kc)
      a[kc] = *(const half8*)&zl[w*16 + rlo][kc*32 + row4*8];
    for (int nt = 0; nt < 32; ++nt) {
      int col = nt*16 + rlo;
      f32x4 acc = {0.f,0.f,0.f,0.f};
      #pragma unroll
      for (int kc = 0; kc < 4; ++kc) {
        half8 b = *(const half8*)&W1t_l[(size_t)col*128 + kc*32 + row4*8];
        acc = __builtin_amdgcn_mfma_f32_16x16x32_f16(a[kc], b, acc, 0, 0, 0);
      }
      float bias = b1_l[col];
      #pragma unroll
      for (int j = 0; j < 4; ++j)
        y1[w*16 + row4*4 + j][col] = (f16)gelu_tanh(acc[j] + bias);
    }
  }
  __syncthreads();
  {  // hout = y1 @ W2 + b2 + hin
    half8 a[16];
    #pragma unroll
    for (int kc = 0; kc < 16; ++kc)
      a[kc] = *(const half8*)&y1[w*16 + rlo][kc*32 + row4*8];
    #pragma unroll
    for (int nt = 0; nt < 8; ++nt) {
      int col = nt*16 + rlo;
      f32x4 acc = {0.f,0.f,0.f,0.f};
      #pragma unroll
      for (int kc = 0; kc < 16; ++kc) {
        half8 b = *(const half8*)&W2t_l[(size_t)col*512 + kc*32 + row4*8];
        acc = __builtin_amdgcn_mfma_f32_16x16x32_f16(a[kc], b, acc, 0, 0, 0);
      }
      float bias = b2_l[col];
      #pragma unroll
      for (int j = 0; j < 4; ++j) {
        size_t n = (size_t)(n0 + w*16 + row4*4 + j);
        hout[n*128 + col] = acc[j] + bias + hin[n*128 + col];
      }
    }
  }
}

// ---------------- readout ------------------------------------------------------------
__global__ __launch_bounds__(256) void readout_kernel(const float* __restrict__ h,
    const float* __restrict__ Wr, const float* __restrict__ br, float* __restrict__ out) {
  int n = blockIdx.x*256 + threadIdx.x;
  f32x4 acc = {0.f,0.f,0.f,0.f};
  #pragma unroll
  for (int cb = 0; cb < 32; ++cb) {
    f32x4 hv = *(const f32x4*)(h + (size_t)n*128 + cb*4);
    f32x4 wv = *(const f32x4*)(Wr + cb*4);
    acc += hv*wv;
  }
  out[n] = acc[0]+acc[1]+acc[2]+acc[3] + br[0];
}

extern "C" void kernel_launch(void* const* d_in, const int* in_sizes, int n_in,
                              void* d_out, int out_size, void* d_ws, size_t ws_size,
                              hipStream_t stream) {
  const float* x   = (const float*)d_in[0];
  const float* pos = (const float*)d_in[1];
  const float* We  = (const float*)d_in[3];
  const float* Wb1 = (const float*)d_in[4];
  const float* bb1 = (const float*)d_in[5];
  const float* Wb2 = (const float*)d_in[6];
  const float* bb2 = (const float*)d_in[7];
  const float* Wk  = (const float*)d_in[8];
  const float* lng = (const float*)d_in[9];
  const float* lnb = (const float*)d_in[10];
  const float* W1  = (const float*)d_in[11];
  const float* b1  = (const float*)d_in[12];
  const float* W2  = (const float*)d_in[13];
  const float* b2  = (const float*)d_in[14];
  const float* Wr  = (const float*)d_in[15];
  const float* br  = (const float*)d_in[16];
  float* out = (float*)d_out;

  char* p = (char*)d_ws;
  int*   srci  = (int*)p;     p += (size_t)EE*4;
  float* dedge = (float*)p;   p += (size_t)EE*4;
  f16*   kernA = (f16*)p;     p += (size_t)EE*128*2;
  float* hA    = (float*)p;   p += (size_t)NN*128*4;
  float* hB    = (float*)p;   p += (size_t)NN*128*4;
  float* agg   = (float*)p;   p += (size_t)NN*128*4;
  f16* Wb2t    = (f16*)p;     p += (size_t)16384*2;
  f16* Wkt     = (f16*)p;     p += (size_t)65536*2;
  f16* W1t     = (f16*)p;     p += (size_t)262144*2;
  f16* W2t     = (f16*)p;     p += (size_t)262144*2;

  prep_kernel<<<2368, 256, 0, stream>>>(Wb2, Wk, W1, W2, Wb2t, Wkt, W1t, W2t);
  knn_kernel<<<NN/4, 256, 0, stream>>>(pos, srci, dedge);
  basis_kernel<<<EE/64, 256, 0, stream>>>(dedge, Wb1, bb1, Wb2t, bb2, kernA);
  embed_kernel<<<NN/8, 256, 0, stream>>>(x, We, hA);
  float* hin = hA;
  for (int lyr = 0; lyr < NL; ++lyr) {
    float* hout = (hin == hA) ? hB : hA;
    conv_kernel<<<NN/64, 256, 0, stream>>>(kernA, Wkt + lyr*16384, srci, hin, agg);
    mlp_kernel<<<NN/64, 256, 0, stream>>>(agg, hin, lng + lyr*128, lnb + lyr*128,
        W1t + (size_t)lyr*65536, b1 + lyr*512, W2t + (size_t)lyr*65536, b2 + lyr*128, hout);
    hin = hout;
  }
  readout_kernel<<<NN/256, 256, 0, stream>>>(hin, Wr, br, out);
}

// Round 5
// 454.201 us; speedup vs baseline: 3.3078x; 1.1564x over previous
//
#include <hip/hip_runtime.h>
#include <hip/hip_bf16.h>

#define NN 16384
#define GG 2048
#define KNN 16
#define EE (NN*KNN)
#define NL 4

typedef _Float16 f16;
typedef _Float16 half8 __attribute__((ext_vector_type(8)));
typedef _Float16 half4 __attribute__((ext_vector_type(4)));
typedef float f32x4 __attribute__((ext_vector_type(4)));
typedef unsigned long long u64;

// gelu tanh-approx in sigmoid form: x*sigmoid(2y), y=a(x+b x^3), a=0.79788456, b=0.044715
__device__ __forceinline__ float gelu_tanh(float x) {
  float s = x*x;
  float u = __fmaf_rn(-0.0713548194f, s, -1.5957691216f);   // -2ab*s - 2a
  float p = __expf(x*u);
  return x * __builtin_amdgcn_rcpf(1.0f + p);
}

// ---------------- kNN: one WAVE per node -------------------------------------------
#define INS(kk) { bool sw = key < kk; u64 tmp = kk; kk = sw ? key : kk; key = sw ? tmp : key; }

__global__ __launch_bounds__(256) void knn_kernel(const float* __restrict__ pos,
    int* __restrict__ srci, float* __restrict__ dedge) {
  __shared__ float px[GG], py[GG], pz[GG];
  int tid = threadIdx.x;
  int node = blockIdx.x*4 + (tid >> 6);
  int lane = tid & 63;
  int base = (node >> 11) << 11;
  for (int j = tid; j < GG; j += 256) {
    px[j] = pos[(base+j)*3+0];
    py[j] = pos[(base+j)*3+1];
    pz[j] = pos[(base+j)*3+2];
  }
  __syncthreads();
  int li = node & (GG-1);
  float qx = px[li], qy = py[li], qz = pz[li];

  u64 c0=~0ull,c1=~0ull,c2=~0ull,c3=~0ull,c4=~0ull,c5=~0ull;
  for (int it = 0; it < 32; ++it) {
    int j = it*64 + lane;
    float dx = __fsub_rn(qx, px[j]);
    float dy = __fsub_rn(qy, py[j]);
    float dz = __fsub_rn(qz, pz[j]);
    float d2 = __fadd_rn(__fadd_rn(__fmul_rn(dx,dx), __fmul_rn(dy,dy)), __fmul_rn(dz,dz));
    u64 key = ((u64)__float_as_uint(d2) << 32) | (unsigned)j;
    INS(c0) INS(c1) INS(c2) INS(c3) INS(c4) INS(c5)
  }
  u64 res = 0;
  int pc = 0;
  for (int r = 0; r < 16; ++r) {
    u64 cur = c0;
    #pragma unroll
    for (int s = 1; s < 64; s <<= 1) {
      u64 o = __shfl_xor(cur, s, 64);
      cur = (o < cur) ? o : cur;
    }
    bool own = (c0 == cur);
    pc += own ? 1 : 0;
    c0 = own?c1:c0; c1 = own?c2:c1; c2 = own?c3:c2;
    c3 = own?c4:c3; c4 = own?c5:c4; c5 = own?~0ull:c5;
    res = (lane == r) ? cur : res;
  }
  if (__any(pc >= 6)) {
    u64 k0=~0ull,k1=~0ull,k2=~0ull,k3=~0ull,k4=~0ull,k5=~0ull,k6=~0ull,k7=~0ull,
        k8=~0ull,k9=~0ull,k10=~0ull,k11=~0ull,k12=~0ull,k13=~0ull,k14=~0ull,k15=~0ull;
    for (int it = 0; it < 32; ++it) {
      int j = it*64 + lane;
      float dx = __fsub_rn(qx, px[j]);
      float dy = __fsub_rn(qy, py[j]);
      float dz = __fsub_rn(qz, pz[j]);
      float d2 = __fadd_rn(__fadd_rn(__fmul_rn(dx,dx), __fmul_rn(dy,dy)), __fmul_rn(dz,dz));
      u64 key = ((u64)__float_as_uint(d2) << 32) | (unsigned)j;
      if (key < k15) {
        INS(k0) INS(k1) INS(k2) INS(k3) INS(k4) INS(k5) INS(k6) INS(k7)
        INS(k8) INS(k9) INS(k10) INS(k11) INS(k12) INS(k13) INS(k14) INS(k15)
      }
    }
    res = 0;
    for (int r = 0; r < 16; ++r) {
      u64 cur = k0;
      #pragma unroll
      for (int s = 1; s < 64; s <<= 1) {
        u64 o = __shfl_xor(cur, s, 64);
        cur = (o < cur) ? o : cur;
      }
      bool own = (k0 == cur);
      k0 = own?k1:k0;  k1 = own?k2:k1;  k2 = own?k3:k2;  k3 = own?k4:k3;
      k4 = own?k5:k4;  k5 = own?k6:k5;  k6 = own?k7:k6;  k7 = own?k8:k7;
      k8 = own?k9:k8;  k9 = own?k10:k9; k10= own?k11:k10; k11= own?k12:k11;
      k12= own?k13:k12; k13= own?k14:k13; k14= own?k15:k14; k15= own?~0ull:k15;
      res = (lane == r) ? cur : res;
    }
  }
  if (lane < KNN) {
    int j = (int)(res & 0xffffffffu);
    float d2 = __uint_as_float((unsigned)(res >> 32));
    srci[node*KNN + lane] = base + j;
    dedge[node*KNN + lane] = sqrtf(__fadd_rn(d2, 1e-12f));
  }
}

// ---------------- weight transpose + f16 convert (transposed [col][k] layouts) -------
__global__ __launch_bounds__(256) void prep_kernel(
    const float* __restrict__ Wb2, const float* __restrict__ Wk,
    const float* __restrict__ W1, const float* __restrict__ W2,
    f16* __restrict__ Wb2t, f16* __restrict__ Wkt,
    f16* __restrict__ W1t, f16* __restrict__ W2t) {
  int i = blockIdx.x*256 + threadIdx.x;
  if (i < 16384) {
    int c = i >> 7, k = i & 127;
    Wb2t[i] = (f16)Wb2[k*128 + c];
    return;
  }
  i -= 16384;
  if (i < 65536) {
    int l = i >> 14, r = i & 16383; int c = r >> 7, k = r & 127;
    Wkt[i] = (f16)Wk[l*16384 + k*128 + c];
    return;
  }
  i -= 65536;
  if (i < 262144) {
    int l = i >> 16, r = i & 65535; int c = r >> 7, k = r & 127;   // c<512,k<128
    W1t[i] = (f16)W1[l*65536 + k*512 + c];
    return;
  }
  i -= 262144;
  if (i < 262144) {
    int l = i >> 16, r = i & 65535; int c = r >> 9, k = r & 511;   // c<128,k<512
    W2t[i] = (f16)W2[l*65536 + k*128 + c];
  }
}

// ---------------- embed: h = x[N,65] @ We[65,128] (f32 VALU) -------------------------
__global__ __launch_bounds__(256) void embed_kernel(const float* __restrict__ x,
    const float* __restrict__ We, float* __restrict__ h) {
  int t = threadIdx.x;
  int n = blockIdx.x*8 + (t >> 5);
  int q = (t & 31) * 4;
  f32x4 acc = {0.f,0.f,0.f,0.f};
  const float* xr = x + n*65;
  for (int k = 0; k < 65; ++k) {
    float xv = xr[k];
    f32x4 wv = *(const f32x4*)(We + k*128 + q);
    acc += xv * wv;
  }
  *(f32x4*)(h + (size_t)n*128 + q) = acc;
}

// ---------------- edge basis v2: zero barriers -------------------------------------
// Each lane computes exactly its own A-frag elements of kb = gelu(poly@Wb1+bb1)
// (the A-frag partition covers each (edge,k) once -> no duplicated work, no LDS
// for kb). Out-tile transpose via LDS is WITHIN-WAVE only -> no __syncthreads.
__global__ __launch_bounds__(256) void basis_kernel(const float* __restrict__ dedge,
    const float* __restrict__ Wb1, const float* __restrict__ bb1,
    const f16* __restrict__ Wb2t, const float* __restrict__ bb2,
    f16* __restrict__ kernA) {
  __shared__ f16 kb[64][136];   // out-tile staging; rows w*16..w*16+15 private to wave w
  int t = threadIdx.x;
  int w = t >> 6, l = t & 63;
  int row4 = l >> 4, rlo = l & 15;
  int e0 = blockIdx.x * 64;
  float d = dedge[e0 + w*16 + rlo];
  float d2 = d*d, d3 = d2*d;
  half8 a[4];
  #pragma unroll
  for (int kc = 0; kc < 4; ++kc) {
    int k0 = kc*32 + row4*8;
    f32x4 w1a = *(const f32x4*)&Wb1[k0],     w1b = *(const f32x4*)&Wb1[k0+4];
    f32x4 w2a = *(const f32x4*)&Wb1[128+k0], w2b = *(const f32x4*)&Wb1[128+k0+4];
    f32x4 w3a = *(const f32x4*)&Wb1[256+k0], w3b = *(const f32x4*)&Wb1[256+k0+4];
    f32x4 bba = *(const f32x4*)&bb1[k0],     bbb = *(const f32x4*)&bb1[k0+4];
    #pragma unroll
    for (int j = 0; j < 4; ++j) {
      a[kc][j]   = (f16)gelu_tanh(d*w1a[j] + d2*w2a[j] + d3*w3a[j] + bba[j]);
      a[kc][4+j] = (f16)gelu_tanh(d*w1b[j] + d2*w2b[j] + d3*w3b[j] + bbb[j]);
    }
  }
  f32x4 acc[8];
  #pragma unroll
  for (int nt = 0; nt < 8; ++nt) {
    acc[nt] = (f32x4){0.f,0.f,0.f,0.f};
    #pragma unroll
    for (int kc = 0; kc < 4; ++kc) {
      half8 b = *(const half8*)&Wb2t[(nt*16 + rlo)*128 + kc*32 + row4*8];
      acc[nt] = __builtin_amdgcn_mfma_f32_16x16x32_f16(a[kc], b, acc[nt], 0, 0, 0);
    }
  }
  #pragma unroll
  for (int nt = 0; nt < 8; ++nt) {
    float bias = bb2[nt*16 + rlo];
    #pragma unroll
    for (int j = 0; j < 4; ++j)
      kb[w*16 + row4*4 + j][nt*16 + rlo] = (f16)gelu_tanh(acc[nt][j] + bias);
  }
  // within-wave RAW on LDS: compiler inserts lgkmcnt wait; no barrier needed
  size_t Tg = (size_t)blockIdx.x*4 + w;
  #pragma unroll
  for (int kc = 0; kc < 4; ++kc) {
    half8 v = *(const half8*)&kb[w*16 + rlo][kc*32 + row4*8];
    *(half8*)&kernA[((Tg*4 + kc)*64 + l)*8] = v;
  }
}

// ---------------- fused layer: conv + LN + MLP + residual, 16 nodes/block -----------
__global__ __launch_bounds__(256) void layer_kernel(const f16* __restrict__ kernA,
    const f16* __restrict__ Wkt_l, const int* __restrict__ srci,
    const float* __restrict__ hin,
    const float* __restrict__ lng, const float* __restrict__ lnb,
    const f16* __restrict__ W1t_l, const float* __restrict__ b1_l,
    const f16* __restrict__ W2t_l, const float* __restrict__ b2_l,
    float* __restrict__ hout) {
  __shared__ float aggl[16][132];   // 8.4KB  conv output (node-local rows)
  __shared__ f16 zl[16][136];       // 4.4KB  LN output
  __shared__ f16 y1h[16][264];      // 8.4KB  half of y1 (256 cols)
  int t = threadIdx.x;
  int w = t >> 6, l = t & 63;
  int row4 = l >> 4, rlo = l & 15;
  int n0 = blockIdx.x * 16;

  { // ---- conv: wave w -> nodes n0 + w*4 .. +3; M-tile = node's 16 edges
    half8 bf[8][4];
    #pragma unroll
    for (int nt = 0; nt < 8; ++nt)
      #pragma unroll
      for (int kc = 0; kc < 4; ++kc)
        bf[nt][kc] = *(const half8*)&Wkt_l[(nt*16 + rlo)*128 + kc*32 + row4*8];
    #pragma unroll
    for (int m = 0; m < 4; ++m) {
      int node = n0 + w*4 + m;
      half8 a[4];
      #pragma unroll
      for (int kc = 0; kc < 4; ++kc)
        a[kc] = *(const half8*)&kernA[(((size_t)node*4 + kc)*64 + l)*8];
      int sidx[4];
      #pragma unroll
      for (int j = 0; j < 4; ++j)
        sidx[j] = srci[node*16 + row4*4 + j];
      #pragma unroll
      for (int nt = 0; nt < 8; ++nt) {
        f32x4 acc = {0.f,0.f,0.f,0.f};
        #pragma unroll
        for (int kc = 0; kc < 4; ++kc)
          acc = __builtin_amdgcn_mfma_f32_16x16x32_f16(a[kc], bf[nt][kc], acc, 0, 0, 0);
        int col = nt*16 + rlo;
        float p = 0.f;
        #pragma unroll
        for (int j = 0; j < 4; ++j)
          p += acc[j] * hin[(size_t)sidx[j]*128 + col];
        p += __shfl_xor(p, 16, 64);
        p += __shfl_xor(p, 32, 64);
        if (l < 16) aggl[w*4 + m][nt*16 + l] = p;
      }
    }
  }
  __syncthreads();
  { // ---- LayerNorm: 16 lanes per row; row = w*4 + row4, lane q = rlo owns 8 cols
    int row = w*4 + row4;
    int cb = rlo*8;
    f32x4 va = *(const f32x4*)&aggl[row][cb];
    f32x4 vb = *(const f32x4*)&aggl[row][cb+4];
    float s = va[0]+va[1]+va[2]+va[3] + vb[0]+vb[1]+vb[2]+vb[3];
    #pragma unroll
    for (int st = 1; st < 16; st <<= 1) s += __shfl_xor(s, st, 64);
    float mu = s * (1.f/128.f);
    f32x4 da = va - mu, db = vb - mu;
    float s2 = da[0]*da[0]+da[1]*da[1]+da[2]*da[2]+da[3]*da[3]
             + db[0]*db[0]+db[1]*db[1]+db[2]*db[2]+db[3]*db[3];
    #pragma unroll
    for (int st = 1; st < 16; st <<= 1) s2 += __shfl_xor(s2, st, 64);
    float inv = rsqrtf(s2*(1.f/128.f) + 1e-5f);
    f32x4 ga = *(const f32x4*)&lng[cb], gb = *(const f32x4*)&lng[cb+4];
    f32x4 ba = *(const f32x4*)&lnb[cb], bb = *(const f32x4*)&lnb[cb+4];
    f32x4 za = da*inv*ga + ba, zb = db*inv*gb + bb;
    half8 hz = { (f16)za[0],(f16)za[1],(f16)za[2],(f16)za[3],
                 (f16)zb[0],(f16)zb[1],(f16)zb[2],(f16)zb[3] };
    *(half8*)&zl[row][cb] = hz;
  }
  __syncthreads();
  // ---- MLP: y1 in two 256-col halves; W2 accumulates in registers across halves
  half8 az[4];
  #pragma unroll
  for (int kc = 0; kc < 4; ++kc)
    az[kc] = *(const half8*)&zl[rlo][kc*32 + row4*8];
  f32x4 acc2[2] = {{0.f,0.f,0.f,0.f},{0.f,0.f,0.f,0.f}};
  #pragma unroll
  for (int h = 0; h < 2; ++h) {
    // W1 half: wave w computes nt = h*16 + w*4 + 0..3  (cols h*256 + w*64 ..)
    #pragma unroll
    for (int ntl = 0; ntl < 4; ++ntl) {
      int nt = h*16 + w*4 + ntl;
      int col = nt*16 + rlo;
      f32x4 acc = {0.f,0.f,0.f,0.f};
      #pragma unroll
      for (int kc = 0; kc < 4; ++kc) {
        half8 b = *(const half8*)&W1t_l[(size_t)col*128 + kc*32 + row4*8];
        acc = __builtin_amdgcn_mfma_f32_16x16x32_f16(az[kc], b, acc, 0, 0, 0);
      }
      float bias = b1_l[col];
      #pragma unroll
      for (int j = 0; j < 4; ++j)
        y1h[row4*4 + j][(w*4 + ntl)*16 + rlo] = (f16)gelu_tanh(acc[j] + bias);
    }
    __syncthreads();
    // W2 partial over k = h*256 .. h*256+255; wave w owns cols w*32 .. +31
    half8 a2[8];
    #pragma unroll
    for (int kc2 = 0; kc2 < 8; ++kc2)
      a2[kc2] = *(const half8*)&y1h[rlo][kc2*32 + row4*8];
    #pragma unroll
    for (int nt2 = 0; nt2 < 2; ++nt2) {
      int c = (w*2 + nt2)*16 + rlo;
      #pragma unroll
      for (int kc2 = 0; kc2 < 8; ++kc2) {
        half8 b = *(const half8*)&W2t_l[(size_t)c*512 + h*256 + kc2*32 + row4*8];
        acc2[nt2] = __builtin_amdgcn_mfma_f32_16x16x32_f16(a2[kc2], b, acc2[nt2], 0, 0, 0);
      }
    }
    __syncthreads();   // y1h reuse in next half
  }
  #pragma unroll
  for (int nt2 = 0; nt2 < 2; ++nt2) {
    int col = (w*2 + nt2)*16 + rlo;
    float bias = b2_l[col];
    #pragma unroll
    for (int j = 0; j < 4; ++j) {
      size_t n = (size_t)(n0 + row4*4 + j);
      hout[n*128 + col] = acc2[nt2][j] + bias + hin[n*128 + col];
    }
  }
}

// ---------------- readout ------------------------------------------------------------
__global__ __launch_bounds__(256) void readout_kernel(const float* __restrict__ h,
    const float* __restrict__ Wr, const float* __restrict__ br, float* __restrict__ out) {
  int n = blockIdx.x*256 + threadIdx.x;
  f32x4 acc = {0.f,0.f,0.f,0.f};
  #pragma unroll
  for (int cb = 0; cb < 32; ++cb) {
    f32x4 hv = *(const f32x4*)(h + (size_t)n*128 + cb*4);
    f32x4 wv = *(const f32x4*)(Wr + cb*4);
    acc += hv*wv;
  }
  out[n] = acc[0]+acc[1]+acc[2]+acc[3] + br[0];
}

extern "C" void kernel_launch(void* const* d_in, const int* in_sizes, int n_in,
                              void* d_out, int out_size, void* d_ws, size_t ws_size,
                              hipStream_t stream) {
  const float* x   = (const float*)d_in[0];
  const float* pos = (const float*)d_in[1];
  const float* We  = (const float*)d_in[3];
  const float* Wb1 = (const float*)d_in[4];
  const float* bb1 = (const float*)d_in[5];
  const float* Wb2 = (const float*)d_in[6];
  const float* bb2 = (const float*)d_in[7];
  const float* Wk  = (const float*)d_in[8];
  const float* lng = (const float*)d_in[9];
  const float* lnb = (const float*)d_in[10];
  const float* W1  = (const float*)d_in[11];
  const float* b1  = (const float*)d_in[12];
  const float* W2  = (const float*)d_in[13];
  const float* b2  = (const float*)d_in[14];
  const float* Wr  = (const float*)d_in[15];
  const float* br  = (const float*)d_in[16];
  float* out = (float*)d_out;

  char* p = (char*)d_ws;
  int*   srci  = (int*)p;     p += (size_t)EE*4;
  float* dedge = (float*)p;   p += (size_t)EE*4;
  f16*   kernA = (f16*)p;     p += (size_t)EE*128*2;
  float* hA    = (float*)p;   p += (size_t)NN*128*4;
  float* hB    = (float*)p;   p += (size_t)NN*128*4;
  f16* Wb2t    = (f16*)p;     p += (size_t)16384*2;
  f16* Wkt     = (f16*)p;     p += (size_t)65536*2;
  f16* W1t     = (f16*)p;     p += (size_t)262144*2;
  f16* W2t     = (f16*)p;     p += (size_t)262144*2;

  prep_kernel<<<2368, 256, 0, stream>>>(Wb2, Wk, W1, W2, Wb2t, Wkt, W1t, W2t);
  knn_kernel<<<NN/4, 256, 0, stream>>>(pos, srci, dedge);
  basis_kernel<<<EE/64, 256, 0, stream>>>(dedge, Wb1, bb1, Wb2t, bb2, kernA);
  embed_kernel<<<NN/8, 256, 0, stream>>>(x, We, hA);
  float* hin = hA;
  for (int lyr = 0; lyr < NL; ++lyr) {
    float* hout = (hin == hA) ? hB : hA;
    layer_kernel<<<NN/16, 256, 0, stream>>>(kernA, Wkt + lyr*16384, srci, hin,
        lng + lyr*128, lnb + lyr*128,
        W1t + (size_t)lyr*65536, b1 + lyr*512, W2t + (size_t)lyr*65536, b2 + lyr*128, hout);
    hin = hout;
  }
  readout_kernel<<<NN/256, 256, 0, stream>>>(hin, Wr, br, out);
}

// Round 6
// 452.398 us; speedup vs baseline: 3.3210x; 1.0040x over previous
//
#include <hip/hip_runtime.h>
#include <hip/hip_bf16.h>

#define NN 16384
#define GG 2048
#define KNN 16
#define EE (NN*KNN)
#define NL 4

typedef _Float16 f16;
typedef _Float16 half8 __attribute__((ext_vector_type(8)));
typedef _Float16 half4 __attribute__((ext_vector_type(4)));
typedef float f32x4 __attribute__((ext_vector_type(4)));
typedef unsigned long long u64;

// gelu tanh-approx in sigmoid form: x*sigmoid(2y), y=a(x+b x^3)
__device__ __forceinline__ float gelu_tanh(float x) {
  float s = x*x;
  float u = __fmaf_rn(-0.0713548194f, s, -1.5957691216f);   // -2ab*s - 2a
  float p = __expf(x*u);
  return x * __builtin_amdgcn_rcpf(1.0f + p);
}

// ---------------- kNN: one WAVE per node -------------------------------------------
#define INS(kk) { bool sw = key < kk; u64 tmp = kk; kk = sw ? key : kk; key = sw ? tmp : key; }

__global__ __launch_bounds__(256) void knn_kernel(const float* __restrict__ pos,
    int* __restrict__ srci, float* __restrict__ dedge) {
  __shared__ float px[GG], py[GG], pz[GG];
  int tid = threadIdx.x;
  int node = blockIdx.x*4 + (tid >> 6);
  int lane = tid & 63;
  int base = (node >> 11) << 11;
  for (int j = tid; j < GG; j += 256) {
    px[j] = pos[(base+j)*3+0];
    py[j] = pos[(base+j)*3+1];
    pz[j] = pos[(base+j)*3+2];
  }
  __syncthreads();
  int li = node & (GG-1);
  float qx = px[li], qy = py[li], qz = pz[li];

  u64 c0=~0ull,c1=~0ull,c2=~0ull,c3=~0ull,c4=~0ull,c5=~0ull;
  for (int it = 0; it < 32; ++it) {
    int j = it*64 + lane;
    float dx = __fsub_rn(qx, px[j]);
    float dy = __fsub_rn(qy, py[j]);
    float dz = __fsub_rn(qz, pz[j]);
    float d2 = __fadd_rn(__fadd_rn(__fmul_rn(dx,dx), __fmul_rn(dy,dy)), __fmul_rn(dz,dz));
    u64 key = ((u64)__float_as_uint(d2) << 32) | (unsigned)j;
    INS(c0) INS(c1) INS(c2) INS(c3) INS(c4) INS(c5)
  }
  u64 res = 0;
  int pc = 0;
  for (int r = 0; r < 16; ++r) {
    u64 cur = c0;
    #pragma unroll
    for (int s = 1; s < 64; s <<= 1) {
      u64 o = __shfl_xor(cur, s, 64);
      cur = (o < cur) ? o : cur;
    }
    bool own = (c0 == cur);
    pc += own ? 1 : 0;
    c0 = own?c1:c0; c1 = own?c2:c1; c2 = own?c3:c2;
    c3 = own?c4:c3; c4 = own?c5:c4; c5 = own?~0ull:c5;
    res = (lane == r) ? cur : res;
  }
  if (__any(pc >= 6)) {
    u64 k0=~0ull,k1=~0ull,k2=~0ull,k3=~0ull,k4=~0ull,k5=~0ull,k6=~0ull,k7=~0ull,
        k8=~0ull,k9=~0ull,k10=~0ull,k11=~0ull,k12=~0ull,k13=~0ull,k14=~0ull,k15=~0ull;
    for (int it = 0; it < 32; ++it) {
      int j = it*64 + lane;
      float dx = __fsub_rn(qx, px[j]);
      float dy = __fsub_rn(qy, py[j]);
      float dz = __fsub_rn(qz, pz[j]);
      float d2 = __fadd_rn(__fadd_rn(__fmul_rn(dx,dx), __fmul_rn(dy,dy)), __fmul_rn(dz,dz));
      u64 key = ((u64)__float_as_uint(d2) << 32) | (unsigned)j;
      if (key < k15) {
        INS(k0) INS(k1) INS(k2) INS(k3) INS(k4) INS(k5) INS(k6) INS(k7)
        INS(k8) INS(k9) INS(k10) INS(k11) INS(k12) INS(k13) INS(k14) INS(k15)
      }
    }
    res = 0;
    for (int r = 0; r < 16; ++r) {
      u64 cur = k0;
      #pragma unroll
      for (int s = 1; s < 64; s <<= 1) {
        u64 o = __shfl_xor(cur, s, 64);
        cur = (o < cur) ? o : cur;
      }
      bool own = (k0 == cur);
      k0 = own?k1:k0;  k1 = own?k2:k1;  k2 = own?k3:k2;  k3 = own?k4:k3;
      k4 = own?k5:k4;  k5 = own?k6:k5;  k6 = own?k7:k6;  k7 = own?k8:k7;
      k8 = own?k9:k8;  k9 = own?k10:k9; k10= own?k11:k10; k11= own?k12:k11;
      k12= own?k13:k12; k13= own?k14:k13; k14= own?k15:k14; k15= own?~0ull:k15;
      res = (lane == r) ? cur : res;
    }
  }
  if (lane < KNN) {
    int j = (int)(res & 0xffffffffu);
    float d2 = __uint_as_float((unsigned)(res >> 32));
    srci[node*KNN + lane] = base + j;
    dedge[node*KNN + lane] = sqrtf(__fadd_rn(d2, 1e-12f));
  }
}

// ---------------- weight transpose + f16 convert (transposed [col][k] layouts) -------
__global__ __launch_bounds__(256) void prep_kernel(
    const float* __restrict__ Wb2, const float* __restrict__ Wk,
    const float* __restrict__ W1, const float* __restrict__ W2,
    f16* __restrict__ Wb2t, f16* __restrict__ Wkt,
    f16* __restrict__ W1t, f16* __restrict__ W2t) {
  int i = blockIdx.x*256 + threadIdx.x;
  if (i < 16384) {
    int c = i >> 7, k = i & 127;
    Wb2t[i] = (f16)Wb2[k*128 + c];
    return;
  }
  i -= 16384;
  if (i < 65536) {
    int l = i >> 14, r = i & 16383; int c = r >> 7, k = r & 127;
    Wkt[i] = (f16)Wk[l*16384 + k*128 + c];
    return;
  }
  i -= 65536;
  if (i < 262144) {
    int l = i >> 16, r = i & 65535; int c = r >> 7, k = r & 127;   // c<512,k<128
    W1t[i] = (f16)W1[l*65536 + k*512 + c];
    return;
  }
  i -= 262144;
  if (i < 262144) {
    int l = i >> 16, r = i & 65535; int c = r >> 9, k = r & 511;   // c<128,k<512
    W2t[i] = (f16)W2[l*65536 + k*128 + c];
  }
}

// ---------------- embed: h = x[N,65] @ We[65,128] (f32 VALU) -------------------------
__global__ __launch_bounds__(256) void embed_kernel(const float* __restrict__ x,
    const float* __restrict__ We, float* __restrict__ h) {
  int t = threadIdx.x;
  int n = blockIdx.x*8 + (t >> 5);
  int q = (t & 31) * 4;
  f32x4 acc = {0.f,0.f,0.f,0.f};
  const float* xr = x + n*65;
  for (int k = 0; k < 65; ++k) {
    float xv = xr[k];
    f32x4 wv = *(const f32x4*)(We + k*128 + q);
    acc += xv * wv;
  }
  *(f32x4*)(h + (size_t)n*128 + q) = acc;
}

// ---------------- edge basis v3: 128-thr blocks for occupancy ----------------------
// 2 waves/block, one 16-edge tile per wave, LDS 8.7KB -> ~16 blocks/CU resident.
// No __syncthreads (LDS rows private per wave).
__global__ __launch_bounds__(128) void basis_kernel(const float* __restrict__ dedge,
    const float* __restrict__ Wb1, const float* __restrict__ bb1,
    const f16* __restrict__ Wb2t, const float* __restrict__ bb2,
    f16* __restrict__ kernA) {
  __shared__ f16 kb[32][136];   // rows w*16..w*16+15 private to wave w
  int t = threadIdx.x;
  int w = t >> 6, l = t & 63;
  int row4 = l >> 4, rlo = l & 15;
  size_t Tg = (size_t)blockIdx.x*2 + w;
  float d = dedge[Tg*16 + rlo];
  float d2 = d*d, d3 = d2*d;
  half8 a[4];
  #pragma unroll
  for (int kc = 0; kc < 4; ++kc) {
    int k0 = kc*32 + row4*8;
    f32x4 w1a = *(const f32x4*)&Wb1[k0],     w1b = *(const f32x4*)&Wb1[k0+4];
    f32x4 w2a = *(const f32x4*)&Wb1[128+k0], w2b = *(const f32x4*)&Wb1[128+k0+4];
    f32x4 w3a = *(const f32x4*)&Wb1[256+k0], w3b = *(const f32x4*)&Wb1[256+k0+4];
    f32x4 bba = *(const f32x4*)&bb1[k0],     bbb = *(const f32x4*)&bb1[k0+4];
    #pragma unroll
    for (int j = 0; j < 4; ++j) {
      a[kc][j]   = (f16)gelu_tanh(d*w1a[j] + d2*w2a[j] + d3*w3a[j] + bba[j]);
      a[kc][4+j] = (f16)gelu_tanh(d*w1b[j] + d2*w2b[j] + d3*w3b[j] + bbb[j]);
    }
  }
  f32x4 acc[8];
  #pragma unroll
  for (int nt = 0; nt < 8; ++nt) {
    acc[nt] = (f32x4){0.f,0.f,0.f,0.f};
    #pragma unroll
    for (int kc = 0; kc < 4; ++kc) {
      half8 b = *(const half8*)&Wb2t[(nt*16 + rlo)*128 + kc*32 + row4*8];
      acc[nt] = __builtin_amdgcn_mfma_f32_16x16x32_f16(a[kc], b, acc[nt], 0, 0, 0);
    }
  }
  #pragma unroll
  for (int nt = 0; nt < 8; ++nt) {
    float bias = bb2[nt*16 + rlo];
    #pragma unroll
    for (int j = 0; j < 4; ++j)
      kb[w*16 + row4*4 + j][nt*16 + rlo] = (f16)gelu_tanh(acc[nt][j] + bias);
  }
  // within-wave RAW on LDS: compiler inserts lgkmcnt wait; no barrier needed
  #pragma unroll
  for (int kc = 0; kc < 4; ++kc) {
    half8 v = *(const half8*)&kb[w*16 + rlo][kc*32 + row4*8];
    *(half8*)&kernA[((Tg*4 + kc)*64 + l)*8] = v;
  }
}

// ---------------- fused layer: conv + LN + MLP + residual, 16 nodes/block -----------
// conv nt-loop split in two halves (bf[4][4] hoist = 64 VGPR) to keep VGPR ~<128.
__global__ __launch_bounds__(256) void layer_kernel(const f16* __restrict__ kernA,
    const f16* __restrict__ Wkt_l, const int* __restrict__ srci,
    const float* __restrict__ hin,
    const float* __restrict__ lng, const float* __restrict__ lnb,
    const f16* __restrict__ W1t_l, const float* __restrict__ b1_l,
    const f16* __restrict__ W2t_l, const float* __restrict__ b2_l,
    float* __restrict__ hout) {
  __shared__ float aggl[16][132];   // 8.4KB  conv output (node-local rows)
  __shared__ f16 zl[16][136];       // 4.4KB  LN output
  __shared__ f16 y1h[16][264];      // 8.4KB  half of y1 (256 cols)
  int t = threadIdx.x;
  int w = t >> 6, l = t & 63;
  int row4 = l >> 4, rlo = l & 15;
  int n0 = blockIdx.x * 16;

  // ---- conv: wave w -> nodes n0 + w*4 .. +3; two nt-halves to bound VGPR use
  #pragma unroll
  for (int hh = 0; hh < 2; ++hh) {
    half8 bf[4][4];
    #pragma unroll
    for (int nt4 = 0; nt4 < 4; ++nt4)
      #pragma unroll
      for (int kc = 0; kc < 4; ++kc)
        bf[nt4][kc] = *(const half8*)&Wkt_l[((hh*4 + nt4)*16 + rlo)*128 + kc*32 + row4*8];
    #pragma unroll
    for (int m = 0; m < 4; ++m) {
      int node = n0 + w*4 + m;
      half8 a[4];
      #pragma unroll
      for (int kc = 0; kc < 4; ++kc)
        a[kc] = *(const half8*)&kernA[(((size_t)node*4 + kc)*64 + l)*8];
      int sidx[4];
      #pragma unroll
      for (int j = 0; j < 4; ++j)
        sidx[j] = srci[node*16 + row4*4 + j];
      #pragma unroll
      for (int nt4 = 0; nt4 < 4; ++nt4) {
        f32x4 acc = {0.f,0.f,0.f,0.f};
        #pragma unroll
        for (int kc = 0; kc < 4; ++kc)
          acc = __builtin_amdgcn_mfma_f32_16x16x32_f16(a[kc], bf[nt4][kc], acc, 0, 0, 0);
        int col = (hh*4 + nt4)*16 + rlo;
        float p = 0.f;
        #pragma unroll
        for (int j = 0; j < 4; ++j)
          p += acc[j] * hin[(size_t)sidx[j]*128 + col];
        p += __shfl_xor(p, 16, 64);
        p += __shfl_xor(p, 32, 64);
        if (l < 16) aggl[w*4 + m][(hh*4 + nt4)*16 + l] = p;
      }
    }
  }
  __syncthreads();
  { // ---- LayerNorm: 16 lanes per row; row = w*4 + row4, lane rlo owns 8 cols
    int row = w*4 + row4;
    int cb = rlo*8;
    f32x4 va = *(const f32x4*)&aggl[row][cb];
    f32x4 vb = *(const f32x4*)&aggl[row][cb+4];
    float s = va[0]+va[1]+va[2]+va[3] + vb[0]+vb[1]+vb[2]+vb[3];
    #pragma unroll
    for (int st = 1; st < 16; st <<= 1) s += __shfl_xor(s, st, 64);
    float mu = s * (1.f/128.f);
    f32x4 da = va - mu, db = vb - mu;
    float s2 = da[0]*da[0]+da[1]*da[1]+da[2]*da[2]+da[3]*da[3]
             + db[0]*db[0]+db[1]*db[1]+db[2]*db[2]+db[3]*db[3];
    #pragma unroll
    for (int st = 1; st < 16; st <<= 1) s2 += __shfl_xor(s2, st, 64);
    float inv = rsqrtf(s2*(1.f/128.f) + 1e-5f);
    f32x4 ga = *(const f32x4*)&lng[cb], gb = *(const f32x4*)&lng[cb+4];
    f32x4 ba = *(const f32x4*)&lnb[cb], bb = *(const f32x4*)&lnb[cb+4];
    f32x4 za = da*inv*ga + ba, zb = db*inv*gb + bb;
    half8 hz = { (f16)za[0],(f16)za[1],(f16)za[2],(f16)za[3],
                 (f16)zb[0],(f16)zb[1],(f16)zb[2],(f16)zb[3] };
    *(half8*)&zl[row][cb] = hz;
  }
  __syncthreads();
  // ---- MLP: y1 in two 256-col halves; W2 accumulates in registers across halves
  half8 az[4];
  #pragma unroll
  for (int kc = 0; kc < 4; ++kc)
    az[kc] = *(const half8*)&zl[rlo][kc*32 + row4*8];
  f32x4 acc2[2] = {{0.f,0.f,0.f,0.f},{0.f,0.f,0.f,0.f}};
  #pragma unroll
  for (int h = 0; h < 2; ++h) {
    #pragma unroll
    for (int ntl = 0; ntl < 4; ++ntl) {
      int nt = h*16 + w*4 + ntl;
      int col = nt*16 + rlo;
      f32x4 acc = {0.f,0.f,0.f,0.f};
      #pragma unroll
      for (int kc = 0; kc < 4; ++kc) {
        half8 b = *(const half8*)&W1t_l[(size_t)col*128 + kc*32 + row4*8];
        acc = __builtin_amdgcn_mfma_f32_16x16x32_f16(az[kc], b, acc, 0, 0, 0);
      }
      float bias = b1_l[col];
      #pragma unroll
      for (int j = 0; j < 4; ++j)
        y1h[row4*4 + j][(w*4 + ntl)*16 + rlo] = (f16)gelu_tanh(acc[j] + bias);
    }
    __syncthreads();
    half8 a2[8];
    #pragma unroll
    for (int kc2 = 0; kc2 < 8; ++kc2)
      a2[kc2] = *(const half8*)&y1h[rlo][kc2*32 + row4*8];
    #pragma unroll
    for (int nt2 = 0; nt2 < 2; ++nt2) {
      int c = (w*2 + nt2)*16 + rlo;
      #pragma unroll
      for (int kc2 = 0; kc2 < 8; ++kc2) {
        half8 b = *(const half8*)&W2t_l[(size_t)c*512 + h*256 + kc2*32 + row4*8];
        acc2[nt2] = __builtin_amdgcn_mfma_f32_16x16x32_f16(a2[kc2], b, acc2[nt2], 0, 0, 0);
      }
    }
    __syncthreads();   // y1h reuse in next half
  }
  #pragma unroll
  for (int nt2 = 0; nt2 < 2; ++nt2) {
    int col = (w*2 + nt2)*16 + rlo;
    float bias = b2_l[col];
    #pragma unroll
    for (int j = 0; j < 4; ++j) {
      size_t n = (size_t)(n0 + row4*4 + j);
      hout[n*128 + col] = acc2[nt2][j] + bias + hin[n*128 + col];
    }
  }
}

// ---------------- readout ------------------------------------------------------------
__global__ __launch_bounds__(256) void readout_kernel(const float* __restrict__ h,
    const float* __restrict__ Wr, const float* __restrict__ br, float* __restrict__ out) {
  int n = blockIdx.x*256 + threadIdx.x;
  f32x4 acc = {0.f,0.f,0.f,0.f};
  #pragma unroll
  for (int cb = 0; cb < 32; ++cb) {
    f32x4 hv = *(const f32x4*)(h + (size_t)n*128 + cb*4);
    f32x4 wv = *(const f32x4*)(Wr + cb*4);
    acc += hv*wv;
  }
  out[n] = acc[0]+acc[1]+acc[2]+acc[3] + br[0];
}

extern "C" void kernel_launch(void* const* d_in, const int* in_sizes, int n_in,
                              void* d_out, int out_size, void* d_ws, size_t ws_size,
                              hipStream_t stream) {
  const float* x   = (const float*)d_in[0];
  const float* pos = (const float*)d_in[1];
  const float* We  = (const float*)d_in[3];
  const float* Wb1 = (const float*)d_in[4];
  const float* bb1 = (const float*)d_in[5];
  const float* Wb2 = (const float*)d_in[6];
  const float* bb2 = (const float*)d_in[7];
  const float* Wk  = (const float*)d_in[8];
  const float* lng = (const float*)d_in[9];
  const float* lnb = (const float*)d_in[10];
  const float* W1  = (const float*)d_in[11];
  const float* b1  = (const float*)d_in[12];
  const float* W2  = (const float*)d_in[13];
  const float* b2  = (const float*)d_in[14];
  const float* Wr  = (const float*)d_in[15];
  const float* br  = (const float*)d_in[16];
  float* out = (float*)d_out;

  char* p = (char*)d_ws;
  int*   srci  = (int*)p;     p += (size_t)EE*4;
  float* dedge = (float*)p;   p += (size_t)EE*4;
  f16*   kernA = (f16*)p;     p += (size_t)EE*128*2;
  float* hA    = (float*)p;   p += (size_t)NN*128*4;
  float* hB    = (float*)p;   p += (size_t)NN*128*4;
  f16* Wb2t    = (f16*)p;     p += (size_t)16384*2;
  f16* Wkt     = (f16*)p;     p += (size_t)65536*2;
  f16* W1t     = (f16*)p;     p += (size_t)262144*2;
  f16* W2t     = (f16*)p;     p += (size_t)262144*2;

  prep_kernel<<<2368, 256, 0, stream>>>(Wb2, Wk, W1, W2, Wb2t, Wkt, W1t, W2t);
  knn_kernel<<<NN/4, 256, 0, stream>>>(pos, srci, dedge);
  basis_kernel<<<EE/32, 128, 0, stream>>>(dedge, Wb1, bb1, Wb2t, bb2, kernA);
  embed_kernel<<<NN/8, 256, 0, stream>>>(x, We, hA);
  float* hin = hA;
  for (int lyr = 0; lyr < NL; ++lyr) {
    float* hout = (hin == hA) ? hB : hA;
    layer_kernel<<<NN/16, 256, 0, stream>>>(kernA, Wkt + lyr*16384, srci, hin,
        lng + lyr*128, lnb + lyr*128,
        W1t + (size_t)lyr*65536, b1 + lyr*512, W2t + (size_t)lyr*65536, b2 + lyr*128, hout);
    hin = hout;
  }
  readout_kernel<<<NN/256, 256, 0, stream>>>(hin, Wr, br, out);
}

// Round 7
// 422.354 us; speedup vs baseline: 3.5572x; 1.0711x over previous
//
#include <hip/hip_runtime.h>
#include <hip/hip_bf16.h>

#define NN 16384
#define GG 2048
#define KNN 16
#define EE (NN*KNN)
#define NL 4

typedef _Float16 f16;
typedef _Float16 half8 __attribute__((ext_vector_type(8)));
typedef _Float16 half4 __attribute__((ext_vector_type(4)));
typedef float f32x4 __attribute__((ext_vector_type(4)));
typedef unsigned long long u64;

// gelu tanh-approx in sigmoid form: x*sigmoid(2y), y=a(x+b x^3)
__device__ __forceinline__ float gelu_tanh(float x) {
  float s = x*x;
  float u = __fmaf_rn(-0.0713548194f, s, -1.5957691216f);   // -2ab*s - 2a
  float p = __expf(x*u);
  return x * __builtin_amdgcn_rcpf(1.0f + p);
}

// ---------------- kNN: one WAVE per node; 4-deep per-lane list + exact fallback -----
#define INS(kk) { bool sw = key < kk; u64 tmp = kk; kk = sw ? key : kk; key = sw ? tmp : key; }

__global__ __launch_bounds__(256) void knn_kernel(const float* __restrict__ pos,
    int* __restrict__ srci, float* __restrict__ dedge) {
  __shared__ float px[GG], py[GG], pz[GG];
  int tid = threadIdx.x;
  int node = blockIdx.x*4 + (tid >> 6);
  int lane = tid & 63;
  int base = (node >> 11) << 11;
  for (int j = tid; j < GG; j += 256) {
    px[j] = pos[(base+j)*3+0];
    py[j] = pos[(base+j)*3+1];
    pz[j] = pos[(base+j)*3+2];
  }
  __syncthreads();
  int li = node & (GG-1);
  float qx = px[li], qy = py[li], qz = pz[li];

  u64 c0=~0ull,c1=~0ull,c2=~0ull,c3=~0ull;
  for (int it = 0; it < 32; ++it) {
    int j = it*64 + lane;
    float dx = __fsub_rn(qx, px[j]);
    float dy = __fsub_rn(qy, py[j]);
    float dz = __fsub_rn(qz, pz[j]);
    float d2 = __fadd_rn(__fadd_rn(__fmul_rn(dx,dx), __fmul_rn(dy,dy)), __fmul_rn(dz,dz));
    u64 key = ((u64)__float_as_uint(d2) << 32) | (unsigned)j;
    INS(c0) INS(c1) INS(c2) INS(c3)
  }
  u64 res = 0;
  int pc = 0;
  for (int r = 0; r < 16; ++r) {
    u64 cur = c0;
    #pragma unroll
    for (int s = 1; s < 64; s <<= 1) {
      u64 o = __shfl_xor(cur, s, 64);
      cur = (o < cur) ? o : cur;
    }
    bool own = (c0 == cur);
    pc += own ? 1 : 0;
    c0 = own?c1:c0; c1 = own?c2:c1; c2 = own?c3:c2; c3 = own?~0ull:c3;
    res = (lane == r) ? cur : res;
  }
  if (__any(pc >= 4)) {
    // exact fallback: 16-deep per-lane list (P ~ 0.7% of nodes; deterministic)
    u64 k0=~0ull,k1=~0ull,k2=~0ull,k3=~0ull,k4=~0ull,k5=~0ull,k6=~0ull,k7=~0ull,
        k8=~0ull,k9=~0ull,k10=~0ull,k11=~0ull,k12=~0ull,k13=~0ull,k14=~0ull,k15=~0ull;
    for (int it = 0; it < 32; ++it) {
      int j = it*64 + lane;
      float dx = __fsub_rn(qx, px[j]);
      float dy = __fsub_rn(qy, py[j]);
      float dz = __fsub_rn(qz, pz[j]);
      float d2 = __fadd_rn(__fadd_rn(__fmul_rn(dx,dx), __fmul_rn(dy,dy)), __fmul_rn(dz,dz));
      u64 key = ((u64)__float_as_uint(d2) << 32) | (unsigned)j;
      if (key < k15) {
        INS(k0) INS(k1) INS(k2) INS(k3) INS(k4) INS(k5) INS(k6) INS(k7)
        INS(k8) INS(k9) INS(k10) INS(k11) INS(k12) INS(k13) INS(k14) INS(k15)
      }
    }
    res = 0;
    for (int r = 0; r < 16; ++r) {
      u64 cur = k0;
      #pragma unroll
      for (int s = 1; s < 64; s <<= 1) {
        u64 o = __shfl_xor(cur, s, 64);
        cur = (o < cur) ? o : cur;
      }
      bool own = (k0 == cur);
      k0 = own?k1:k0;  k1 = own?k2:k1;  k2 = own?k3:k2;  k3 = own?k4:k3;
      k4 = own?k5:k4;  k5 = own?k6:k5;  k6 = own?k7:k6;  k7 = own?k8:k7;
      k8 = own?k9:k8;  k9 = own?k10:k9; k10= own?k11:k10; k11= own?k12:k11;
      k12= own?k13:k12; k13= own?k14:k13; k14= own?k15:k14; k15= own?~0ull:k15;
      res = (lane == r) ? cur : res;
    }
  }
  if (lane < KNN) {
    int j = (int)(res & 0xffffffffu);
    float d2 = __uint_as_float((unsigned)(res >> 32));
    srci[node*KNN + lane] = base + j;
    dedge[node*KNN + lane] = sqrtf(__fadd_rn(d2, 1e-12f));
  }
}

// ---------------- weight transpose + f16 convert (transposed [col][k] layouts) -------
__global__ __launch_bounds__(256) void prep_kernel(
    const float* __restrict__ Wb2, const float* __restrict__ Wk,
    const float* __restrict__ W1, const float* __restrict__ W2,
    f16* __restrict__ Wb2t, f16* __restrict__ Wkt,
    f16* __restrict__ W1t, f16* __restrict__ W2t) {
  int i = blockIdx.x*256 + threadIdx.x;
  if (i < 16384) {
    int c = i >> 7, k = i & 127;
    Wb2t[i] = (f16)Wb2[k*128 + c];
    return;
  }
  i -= 16384;
  if (i < 65536) {
    int l = i >> 14, r = i & 16383; int c = r >> 7, k = r & 127;
    Wkt[i] = (f16)Wk[l*16384 + k*128 + c];
    return;
  }
  i -= 65536;
  if (i < 262144) {
    int l = i >> 16, r = i & 65535; int c = r >> 7, k = r & 127;   // c<512,k<128
    W1t[i] = (f16)W1[l*65536 + k*512 + c];
    return;
  }
  i -= 262144;
  if (i < 262144) {
    int l = i >> 16, r = i & 65535; int c = r >> 9, k = r & 511;   // c<128,k<512
    W2t[i] = (f16)W2[l*65536 + k*128 + c];
  }
}

// ---------------- embed: h = x[N,65] @ We[65,128] (f32 VALU) -------------------------
__global__ __launch_bounds__(256) void embed_kernel(const float* __restrict__ x,
    const float* __restrict__ We, float* __restrict__ h) {
  int t = threadIdx.x;
  int n = blockIdx.x*8 + (t >> 5);
  int q = (t & 31) * 4;
  f32x4 acc = {0.f,0.f,0.f,0.f};
  const float* xr = x + n*65;
  for (int k = 0; k < 65; ++k) {
    float xv = xr[k];
    f32x4 wv = *(const f32x4*)(We + k*128 + q);
    acc += xv * wv;
  }
  *(f32x4*)(h + (size_t)n*128 + q) = acc;
}

// ---------------- edge basis v5: Wb2 staged in LDS (kills B-load latency) -----------
// Theory: prior versions serialized 32 global B-loads/wave at ~60 VGPR (3 in flight)
// -> ~5K cyc exposed latency. LDS-staged B: ds_read_b128, 2-way conflicts (free),
// hidden under gelu. 2 tiles/wave amortizes the 32KB staging.
__global__ __launch_bounds__(256) void basis_kernel(const float* __restrict__ dedge,
    const float* __restrict__ Wb1, const float* __restrict__ bb1,
    const f16* __restrict__ Wb2t, const float* __restrict__ bb2,
    f16* __restrict__ kernA) {
  __shared__ f16 Wb2s[128][136];  // 34.8KB, padded: B-frag ds_read_b128 2-way max
  __shared__ f16 kb[64][136];     // 17.4KB, rows w*16.. private per wave
  int t = threadIdx.x;
  #pragma unroll
  for (int it = 0; it < 8; ++it) {      // stage Wb2t (32KB) coalesced
    int idx = it*256 + t;
    int row = idx >> 4, k8 = (idx & 15) * 8;
    *(half8*)&Wb2s[row][k8] = *(const half8*)&Wb2t[row*128 + k8];
  }
  __syncthreads();
  int w = t >> 6, l = t & 63;
  int row4 = l >> 4, rlo = l & 15;
  #pragma unroll
  for (int tt = 0; tt < 2; ++tt) {
    size_t Tg = (size_t)blockIdx.x*8 + (size_t)w*2 + tt;
    float d = dedge[Tg*16 + rlo];
    float d2 = d*d, d3 = d2*d;
    half8 a[4];
    #pragma unroll
    for (int kc = 0; kc < 4; ++kc) {
      int k0 = kc*32 + row4*8;
      f32x4 w1a = *(const f32x4*)&Wb1[k0],     w1b = *(const f32x4*)&Wb1[k0+4];
      f32x4 w2a = *(const f32x4*)&Wb1[128+k0], w2b = *(const f32x4*)&Wb1[128+k0+4];
      f32x4 w3a = *(const f32x4*)&Wb1[256+k0], w3b = *(const f32x4*)&Wb1[256+k0+4];
      f32x4 bba = *(const f32x4*)&bb1[k0],     bbb = *(const f32x4*)&bb1[k0+4];
      #pragma unroll
      for (int j = 0; j < 4; ++j) {
        a[kc][j]   = (f16)gelu_tanh(d*w1a[j] + d2*w2a[j] + d3*w3a[j] + bba[j]);
        a[kc][4+j] = (f16)gelu_tanh(d*w1b[j] + d2*w2b[j] + d3*w3b[j] + bbb[j]);
      }
    }
    f32x4 acc[8];
    #pragma unroll
    for (int nt = 0; nt < 8; ++nt) {
      acc[nt] = (f32x4){0.f,0.f,0.f,0.f};
      #pragma unroll
      for (int kc = 0; kc < 4; ++kc) {
        half8 b = *(const half8*)&Wb2s[nt*16 + rlo][kc*32 + row4*8];
        acc[nt] = __builtin_amdgcn_mfma_f32_16x16x32_f16(a[kc], b, acc[nt], 0, 0, 0);
      }
    }
    #pragma unroll
    for (int nt = 0; nt < 8; ++nt) {
      float bias = bb2[nt*16 + rlo];
      #pragma unroll
      for (int j = 0; j < 4; ++j)
        kb[w*16 + row4*4 + j][nt*16 + rlo] = (f16)gelu_tanh(acc[nt][j] + bias);
    }
    // within-wave RAW on LDS: compiler inserts lgkmcnt wait; no barrier needed
    #pragma unroll
    for (int kc = 0; kc < 4; ++kc) {
      half8 v = *(const half8*)&kb[w*16 + rlo][kc*32 + row4*8];
      *(half8*)&kernA[((Tg*4 + kc)*64 + l)*8] = v;
    }
  }
}

// ---------------- fused layer: conv + LN + MLP + residual, 16 nodes/block -----------
__global__ __launch_bounds__(256) void layer_kernel(const f16* __restrict__ kernA,
    const f16* __restrict__ Wkt_l, const int* __restrict__ srci,
    const float* __restrict__ hin,
    const float* __restrict__ lng, const float* __restrict__ lnb,
    const f16* __restrict__ W1t_l, const float* __restrict__ b1_l,
    const f16* __restrict__ W2t_l, const float* __restrict__ b2_l,
    float* __restrict__ hout) {
  __shared__ float aggl[16][132];   // 8.4KB  conv output (node-local rows)
  __shared__ f16 zl[16][136];       // 4.4KB  LN output
  __shared__ f16 y1h[16][264];      // 8.4KB  half of y1 (256 cols)
  int t = threadIdx.x;
  int w = t >> 6, l = t & 63;
  int row4 = l >> 4, rlo = l & 15;
  int n0 = blockIdx.x * 16;

  // ---- conv: wave w -> nodes n0 + w*4 .. +3; two nt-halves to bound VGPR use
  #pragma unroll
  for (int hh = 0; hh < 2; ++hh) {
    half8 bf[4][4];
    #pragma unroll
    for (int nt4 = 0; nt4 < 4; ++nt4)
      #pragma unroll
      for (int kc = 0; kc < 4; ++kc)
        bf[nt4][kc] = *(const half8*)&Wkt_l[((hh*4 + nt4)*16 + rlo)*128 + kc*32 + row4*8];
    #pragma unroll
    for (int m = 0; m < 4; ++m) {
      int node = n0 + w*4 + m;
      half8 a[4];
      #pragma unroll
      for (int kc = 0; kc < 4; ++kc)
        a[kc] = *(const half8*)&kernA[(((size_t)node*4 + kc)*64 + l)*8];
      int sidx[4];
      #pragma unroll
      for (int j = 0; j < 4; ++j)
        sidx[j] = srci[node*16 + row4*4 + j];
      #pragma unroll
      for (int nt4 = 0; nt4 < 4; ++nt4) {
        f32x4 acc = {0.f,0.f,0.f,0.f};
        #pragma unroll
        for (int kc = 0; kc < 4; ++kc)
          acc = __builtin_amdgcn_mfma_f32_16x16x32_f16(a[kc], bf[nt4][kc], acc, 0, 0, 0);
        int col = (hh*4 + nt4)*16 + rlo;
        float p = 0.f;
        #pragma unroll
        for (int j = 0; j < 4; ++j)
          p += acc[j] * hin[(size_t)sidx[j]*128 + col];
        p += __shfl_xor(p, 16, 64);
        p += __shfl_xor(p, 32, 64);
        if (l < 16) aggl[w*4 + m][(hh*4 + nt4)*16 + l] = p;
      }
    }
  }
  __syncthreads();
  { // ---- LayerNorm: 16 lanes per row; row = w*4 + row4, lane rlo owns 8 cols
    int row = w*4 + row4;
    int cb = rlo*8;
    f32x4 va = *(const f32x4*)&aggl[row][cb];
    f32x4 vb = *(const f32x4*)&aggl[row][cb+4];
    float s = va[0]+va[1]+va[2]+va[3] + vb[0]+vb[1]+vb[2]+vb[3];
    #pragma unroll
    for (int st = 1; st < 16; st <<= 1) s += __shfl_xor(s, st, 64);
    float mu = s * (1.f/128.f);
    f32x4 da = va - mu, db = vb - mu;
    float s2 = da[0]*da[0]+da[1]*da[1]+da[2]*da[2]+da[3]*da[3]
             + db[0]*db[0]+db[1]*db[1]+db[2]*db[2]+db[3]*db[3];
    #pragma unroll
    for (int st = 1; st < 16; st <<= 1) s2 += __shfl_xor(s2, st, 64);
    float inv = rsqrtf(s2*(1.f/128.f) + 1e-5f);
    f32x4 ga = *(const f32x4*)&lng[cb], gb = *(const f32x4*)&lng[cb+4];
    f32x4 ba = *(const f32x4*)&lnb[cb], bb = *(const f32x4*)&lnb[cb+4];
    f32x4 za = da*inv*ga + ba, zb = db*inv*gb + bb;
    half8 hz = { (f16)za[0],(f16)za[1],(f16)za[2],(f16)za[3],
                 (f16)zb[0],(f16)zb[1],(f16)zb[2],(f16)zb[3] };
    *(half8*)&zl[row][cb] = hz;
  }
  __syncthreads();
  // ---- MLP: y1 in two 256-col halves; W2 accumulates in registers across halves
  half8 az[4];
  #pragma unroll
  for (int kc = 0; kc < 4; ++kc)
    az[kc] = *(const half8*)&zl[rlo][kc*32 + row4*8];
  f32x4 acc2[2] = {{0.f,0.f,0.f,0.f},{0.f,0.f,0.f,0.f}};
  #pragma unroll
  for (int h = 0; h < 2; ++h) {
    #pragma unroll
    for (int ntl = 0; ntl < 4; ++ntl) {
      int nt = h*16 + w*4 + ntl;
      int col = nt*16 + rlo;
      f32x4 acc = {0.f,0.f,0.f,0.f};
      #pragma unroll
      for (int kc = 0; kc < 4; ++kc) {
        half8 b = *(const half8*)&W1t_l[(size_t)col*128 + kc*32 + row4*8];
        acc = __builtin_amdgcn_mfma_f32_16x16x32_f16(az[kc], b, acc, 0, 0, 0);
      }
      float bias = b1_l[col];
      #pragma unroll
      for (int j = 0; j < 4; ++j)
        y1h[row4*4 + j][(w*4 + ntl)*16 + rlo] = (f16)gelu_tanh(acc[j] + bias);
    }
    __syncthreads();
    half8 a2[8];
    #pragma unroll
    for (int kc2 = 0; kc2 < 8; ++kc2)
      a2[kc2] = *(const half8*)&y1h[rlo][kc2*32 + row4*8];
    #pragma unroll
    for (int nt2 = 0; nt2 < 2; ++nt2) {
      int c = (w*2 + nt2)*16 + rlo;
      #pragma unroll
      for (int kc2 = 0; kc2 < 8; ++kc2) {
        half8 b = *(const half8*)&W2t_l[(size_t)c*512 + h*256 + kc2*32 + row4*8];
        acc2[nt2] = __builtin_amdgcn_mfma_f32_16x16x32_f16(a2[kc2], b, acc2[nt2], 0, 0, 0);
      }
    }
    __syncthreads();   // y1h reuse in next half
  }
  #pragma unroll
  for (int nt2 = 0; nt2 < 2; ++nt2) {
    int col = (w*2 + nt2)*16 + rlo;
    float bias = b2_l[col];
    #pragma unroll
    for (int j = 0; j < 4; ++j) {
      size_t n = (size_t)(n0 + row4*4 + j);
      hout[n*128 + col] = acc2[nt2][j] + bias + hin[n*128 + col];
    }
  }
}

// ---------------- readout ------------------------------------------------------------
__global__ __launch_bounds__(256) void readout_kernel(const float* __restrict__ h,
    const float* __restrict__ Wr, const float* __restrict__ br, float* __restrict__ out) {
  int n = blockIdx.x*256 + threadIdx.x;
  f32x4 acc = {0.f,0.f,0.f,0.f};
  #pragma unroll
  for (int cb = 0; cb < 32; ++cb) {
    f32x4 hv = *(const f32x4*)(h + (size_t)n*128 + cb*4);
    f32x4 wv = *(const f32x4*)(Wr + cb*4);
    acc += hv*wv;
  }
  out[n] = acc[0]+acc[1]+acc[2]+acc[3] + br[0];
}

extern "C" void kernel_launch(void* const* d_in, const int* in_sizes, int n_in,
                              void* d_out, int out_size, void* d_ws, size_t ws_size,
                              hipStream_t stream) {
  const float* x   = (const float*)d_in[0];
  const float* pos = (const float*)d_in[1];
  const float* We  = (const float*)d_in[3];
  const float* Wb1 = (const float*)d_in[4];
  const float* bb1 = (const float*)d_in[5];
  const float* Wb2 = (const float*)d_in[6];
  const float* bb2 = (const float*)d_in[7];
  const float* Wk  = (const float*)d_in[8];
  const float* lng = (const float*)d_in[9];
  const float* lnb = (const float*)d_in[10];
  const float* W1  = (const float*)d_in[11];
  const float* b1  = (const float*)d_in[12];
  const float* W2  = (const float*)d_in[13];
  const float* b2  = (const float*)d_in[14];
  const float* Wr  = (const float*)d_in[15];
  const float* br  = (const float*)d_in[16];
  float* out = (float*)d_out;

  char* p = (char*)d_ws;
  int*   srci  = (int*)p;     p += (size_t)EE*4;
  float* dedge = (float*)p;   p += (size_t)EE*4;
  f16*   kernA = (f16*)p;     p += (size_t)EE*128*2;
  float* hA    = (float*)p;   p += (size_t)NN*128*4;
  float* hB    = (float*)p;   p += (size_t)NN*128*4;
  f16* Wb2t    = (f16*)p;     p += (size_t)16384*2;
  f16* Wkt     = (f16*)p;     p += (size_t)65536*2;
  f16* W1t     = (f16*)p;     p += (size_t)262144*2;
  f16* W2t     = (f16*)p;     p += (size_t)262144*2;

  prep_kernel<<<2368, 256, 0, stream>>>(Wb2, Wk, W1, W2, Wb2t, Wkt, W1t, W2t);
  knn_kernel<<<NN/4, 256, 0, stream>>>(pos, srci, dedge);
  basis_kernel<<<2048, 256, 0, stream>>>(dedge, Wb1, bb1, Wb2t, bb2, kernA);
  embed_kernel<<<NN/8, 256, 0, stream>>>(x, We, hA);
  float* hin = hA;
  for (int lyr = 0; lyr < NL; ++lyr) {
    float* hout = (hin == hA) ? hB : hA;
    layer_kernel<<<NN/16, 256, 0, stream>>>(kernA, Wkt + lyr*16384, srci, hin,
        lng + lyr*128, lnb + lyr*128,
        W1t + (size_t)lyr*65536, b1 + lyr*512, W2t + (size_t)lyr*65536, b2 + lyr*128, hout);
    hin = hout;
  }
  readout_kernel<<<NN/256, 256, 0, stream>>>(hin, Wr, br, out);
}

// Round 8
// 419.976 us; speedup vs baseline: 3.5773x; 1.0057x over previous
//
#include <hip/hip_runtime.h>
#include <hip/hip_bf16.h>

#define NN 16384
#define GG 2048
#define KNN 16
#define EE (NN*KNN)
#define NL 4

typedef _Float16 f16;
typedef _Float16 half8 __attribute__((ext_vector_type(8)));
typedef _Float16 half4 __attribute__((ext_vector_type(4)));
typedef float f32x4 __attribute__((ext_vector_type(4)));
typedef unsigned long long u64;

// gelu tanh-approx in sigmoid form: x*sigmoid(2y), y=a(x+b x^3)
__device__ __forceinline__ float gelu_tanh(float x) {
  float s = x*x;
  float u = __fmaf_rn(-0.0713548194f, s, -1.5957691216f);   // -2ab*s - 2a
  float p = __expf(x*u);
  return x * __builtin_amdgcn_rcpf(1.0f + p);
}

// ---------------- kNN: one WAVE per node; NO LDS (pos is L2-resident, reads are
// per-lane coalesced, not broadcast). Zero barriers -> occupancy capped only by VGPR.
#define INS(kk) { bool sw = key < kk; u64 tmp = kk; kk = sw ? key : kk; key = sw ? tmp : key; }

__global__ __launch_bounds__(256) void knn_kernel(const float* __restrict__ pos,
    int* __restrict__ srci, float* __restrict__ dedge) {
  int tid = threadIdx.x;
  int node = blockIdx.x*4 + (tid >> 6);
  int lane = tid & 63;
  int base = node & ~(GG-1);
  float qx = pos[(size_t)node*3+0], qy = pos[(size_t)node*3+1], qz = pos[(size_t)node*3+2];

  u64 c0=~0ull,c1=~0ull,c2=~0ull,c3=~0ull;
  for (int it = 0; it < 32; ++it) {
    int j = it*64 + lane;
    const float* pr = pos + (size_t)(base+j)*3;
    float dx = __fsub_rn(qx, pr[0]);
    float dy = __fsub_rn(qy, pr[1]);
    float dz = __fsub_rn(qz, pr[2]);
    float d2 = __fadd_rn(__fadd_rn(__fmul_rn(dx,dx), __fmul_rn(dy,dy)), __fmul_rn(dz,dz));
    u64 key = ((u64)__float_as_uint(d2) << 32) | (unsigned)j;
    INS(c0) INS(c1) INS(c2) INS(c3)
  }
  u64 res = 0;
  int pc = 0;
  for (int r = 0; r < 16; ++r) {
    u64 cur = c0;
    #pragma unroll
    for (int s = 1; s < 64; s <<= 1) {
      u64 o = __shfl_xor(cur, s, 64);
      cur = (o < cur) ? o : cur;
    }
    bool own = (c0 == cur);
    pc += own ? 1 : 0;
    c0 = own?c1:c0; c1 = own?c2:c1; c2 = own?c3:c2; c3 = own?~0ull:c3;
    res = (lane == r) ? cur : res;
  }
  if (__any(pc >= 4)) {
    // exact fallback: 16-deep per-lane list (P ~ 0.7% of nodes; deterministic)
    u64 k0=~0ull,k1=~0ull,k2=~0ull,k3=~0ull,k4=~0ull,k5=~0ull,k6=~0ull,k7=~0ull,
        k8=~0ull,k9=~0ull,k10=~0ull,k11=~0ull,k12=~0ull,k13=~0ull,k14=~0ull,k15=~0ull;
    for (int it = 0; it < 32; ++it) {
      int j = it*64 + lane;
      const float* pr = pos + (size_t)(base+j)*3;
      float dx = __fsub_rn(qx, pr[0]);
      float dy = __fsub_rn(qy, pr[1]);
      float dz = __fsub_rn(qz, pr[2]);
      float d2 = __fadd_rn(__fadd_rn(__fmul_rn(dx,dx), __fmul_rn(dy,dy)), __fmul_rn(dz,dz));
      u64 key = ((u64)__float_as_uint(d2) << 32) | (unsigned)j;
      if (key < k15) {
        INS(k0) INS(k1) INS(k2) INS(k3) INS(k4) INS(k5) INS(k6) INS(k7)
        INS(k8) INS(k9) INS(k10) INS(k11) INS(k12) INS(k13) INS(k14) INS(k15)
      }
    }
    res = 0;
    for (int r = 0; r < 16; ++r) {
      u64 cur = k0;
      #pragma unroll
      for (int s = 1; s < 64; s <<= 1) {
        u64 o = __shfl_xor(cur, s, 64);
        cur = (o < cur) ? o : cur;
      }
      bool own = (k0 == cur);
      k0 = own?k1:k0;  k1 = own?k2:k1;  k2 = own?k3:k2;  k3 = own?k4:k3;
      k4 = own?k5:k4;  k5 = own?k6:k5;  k6 = own?k7:k6;  k7 = own?k8:k7;
      k8 = own?k9:k8;  k9 = own?k10:k9; k10= own?k11:k10; k11= own?k12:k11;
      k12= own?k13:k12; k13= own?k14:k13; k14= own?k15:k14; k15= own?~0ull:k15;
      res = (lane == r) ? cur : res;
    }
  }
  if (lane < KNN) {
    int j = (int)(res & 0xffffffffu);
    float d2 = __uint_as_float((unsigned)(res >> 32));
    srci[node*KNN + lane] = base + j;
    dedge[node*KNN + lane] = sqrtf(__fadd_rn(d2, 1e-12f));
  }
}

// ---------------- weight transpose + f16 convert (transposed [col][k] layouts) -------
__global__ __launch_bounds__(256) void prep_kernel(
    const float* __restrict__ Wb2, const float* __restrict__ Wk,
    const float* __restrict__ W1, const float* __restrict__ W2,
    f16* __restrict__ Wb2t, f16* __restrict__ Wkt,
    f16* __restrict__ W1t, f16* __restrict__ W2t) {
  int i = blockIdx.x*256 + threadIdx.x;
  if (i < 16384) {
    int c = i >> 7, k = i & 127;
    Wb2t[i] = (f16)Wb2[k*128 + c];
    return;
  }
  i -= 16384;
  if (i < 65536) {
    int l = i >> 14, r = i & 16383; int c = r >> 7, k = r & 127;
    Wkt[i] = (f16)Wk[l*16384 + k*128 + c];
    return;
  }
  i -= 65536;
  if (i < 262144) {
    int l = i >> 16, r = i & 65535; int c = r >> 7, k = r & 127;   // c<512,k<128
    W1t[i] = (f16)W1[l*65536 + k*512 + c];
    return;
  }
  i -= 262144;
  if (i < 262144) {
    int l = i >> 16, r = i & 65535; int c = r >> 9, k = r & 511;   // c<128,k<512
    W2t[i] = (f16)W2[l*65536 + k*128 + c];
  }
}

// ---------------- embed: h = x[N,65] @ We[65,128] (f32 VALU) -------------------------
__global__ __launch_bounds__(256) void embed_kernel(const float* __restrict__ x,
    const float* __restrict__ We, float* __restrict__ h) {
  int t = threadIdx.x;
  int n = blockIdx.x*8 + (t >> 5);
  int q = (t & 31) * 4;
  f32x4 acc = {0.f,0.f,0.f,0.f};
  const float* xr = x + n*65;
  for (int k = 0; k < 65; ++k) {
    float xv = xr[k];
    f32x4 wv = *(const f32x4*)(We + k*128 + q);
    acc += xv * wv;
  }
  *(f32x4*)(h + (size_t)n*128 + q) = acc;
}

// ---------------- edge basis v5: Wb2 staged in LDS (kills B-load latency) -----------
__global__ __launch_bounds__(256) void basis_kernel(const float* __restrict__ dedge,
    const float* __restrict__ Wb1, const float* __restrict__ bb1,
    const f16* __restrict__ Wb2t, const float* __restrict__ bb2,
    f16* __restrict__ kernA) {
  __shared__ f16 Wb2s[128][136];  // 34.8KB, padded: B-frag ds_read_b128 2-way max
  __shared__ f16 kb[64][136];     // 17.4KB, rows w*16.. private per wave
  int t = threadIdx.x;
  #pragma unroll
  for (int it = 0; it < 8; ++it) {      // stage Wb2t (32KB) coalesced
    int idx = it*256 + t;
    int row = idx >> 4, k8 = (idx & 15) * 8;
    *(half8*)&Wb2s[row][k8] = *(const half8*)&Wb2t[row*128 + k8];
  }
  __syncthreads();
  int w = t >> 6, l = t & 63;
  int row4 = l >> 4, rlo = l & 15;
  #pragma unroll
  for (int tt = 0; tt < 2; ++tt) {
    size_t Tg = (size_t)blockIdx.x*8 + (size_t)w*2 + tt;
    float d = dedge[Tg*16 + rlo];
    float d2 = d*d, d3 = d2*d;
    half8 a[4];
    #pragma unroll
    for (int kc = 0; kc < 4; ++kc) {
      int k0 = kc*32 + row4*8;
      f32x4 w1a = *(const f32x4*)&Wb1[k0],     w1b = *(const f32x4*)&Wb1[k0+4];
      f32x4 w2a = *(const f32x4*)&Wb1[128+k0], w2b = *(const f32x4*)&Wb1[128+k0+4];
      f32x4 w3a = *(const f32x4*)&Wb1[256+k0], w3b = *(const f32x4*)&Wb1[256+k0+4];
      f32x4 bba = *(const f32x4*)&bb1[k0],     bbb = *(const f32x4*)&bb1[k0+4];
      #pragma unroll
      for (int j = 0; j < 4; ++j) {
        a[kc][j]   = (f16)gelu_tanh(d*w1a[j] + d2*w2a[j] + d3*w3a[j] + bba[j]);
        a[kc][4+j] = (f16)gelu_tanh(d*w1b[j] + d2*w2b[j] + d3*w3b[j] + bbb[j]);
      }
    }
    f32x4 acc[8];
    #pragma unroll
    for (int nt = 0; nt < 8; ++nt) {
      acc[nt] = (f32x4){0.f,0.f,0.f,0.f};
      #pragma unroll
      for (int kc = 0; kc < 4; ++kc) {
        half8 b = *(const half8*)&Wb2s[nt*16 + rlo][kc*32 + row4*8];
        acc[nt] = __builtin_amdgcn_mfma_f32_16x16x32_f16(a[kc], b, acc[nt], 0, 0, 0);
      }
    }
    #pragma unroll
    for (int nt = 0; nt < 8; ++nt) {
      float bias = bb2[nt*16 + rlo];
      #pragma unroll
      for (int j = 0; j < 4; ++j)
        kb[w*16 + row4*4 + j][nt*16 + rlo] = (f16)gelu_tanh(acc[nt][j] + bias);
    }
    // within-wave RAW on LDS: compiler inserts lgkmcnt wait; no barrier needed
    #pragma unroll
    for (int kc = 0; kc < 4; ++kc) {
      half8 v = *(const half8*)&kb[w*16 + rlo][kc*32 + row4*8];
      *(half8*)&kernA[((Tg*4 + kc)*64 + l)*8] = v;
    }
  }
}

// ---------------- fused layer: conv + LN + MLP + residual, 16 nodes/block -----------
// MLP single-pass (full 512-col y1): 3 barriers total (was 5).
__global__ __launch_bounds__(256) void layer_kernel(const f16* __restrict__ kernA,
    const f16* __restrict__ Wkt_l, const int* __restrict__ srci,
    const float* __restrict__ hin,
    const float* __restrict__ lng, const float* __restrict__ lnb,
    const f16* __restrict__ W1t_l, const float* __restrict__ b1_l,
    const f16* __restrict__ W2t_l, const float* __restrict__ b2_l,
    float* __restrict__ hout) {
  __shared__ float aggl[16][132];   // 8.4KB  conv output (node-local rows)
  __shared__ f16 zl[16][136];       // 4.4KB  LN output
  __shared__ f16 y1[16][520];       // 16.6KB full y1
  int t = threadIdx.x;
  int w = t >> 6, l = t & 63;
  int row4 = l >> 4, rlo = l & 15;
  int n0 = blockIdx.x * 16;

  // ---- conv: wave w -> nodes n0 + w*4 .. +3; two nt-halves to bound VGPR use
  #pragma unroll
  for (int hh = 0; hh < 2; ++hh) {
    half8 bf[4][4];
    #pragma unroll
    for (int nt4 = 0; nt4 < 4; ++nt4)
      #pragma unroll
      for (int kc = 0; kc < 4; ++kc)
        bf[nt4][kc] = *(const half8*)&Wkt_l[((hh*4 + nt4)*16 + rlo)*128 + kc*32 + row4*8];
    #pragma unroll
    for (int m = 0; m < 4; ++m) {
      int node = n0 + w*4 + m;
      half8 a[4];
      #pragma unroll
      for (int kc = 0; kc < 4; ++kc)
        a[kc] = *(const half8*)&kernA[(((size_t)node*4 + kc)*64 + l)*8];
      int sidx[4];
      #pragma unroll
      for (int j = 0; j < 4; ++j)
        sidx[j] = srci[node*16 + row4*4 + j];
      #pragma unroll
      for (int nt4 = 0; nt4 < 4; ++nt4) {
        f32x4 acc = {0.f,0.f,0.f,0.f};
        #pragma unroll
        for (int kc = 0; kc < 4; ++kc)
          acc = __builtin_amdgcn_mfma_f32_16x16x32_f16(a[kc], bf[nt4][kc], acc, 0, 0, 0);
        int col = (hh*4 + nt4)*16 + rlo;
        float p = 0.f;
        #pragma unroll
        for (int j = 0; j < 4; ++j)
          p += acc[j] * hin[(size_t)sidx[j]*128 + col];
        p += __shfl_xor(p, 16, 64);
        p += __shfl_xor(p, 32, 64);
        if (l < 16) aggl[w*4 + m][(hh*4 + nt4)*16 + l] = p;
      }
    }
  }
  __syncthreads();
  { // ---- LayerNorm: 16 lanes per row; row = w*4 + row4, lane rlo owns 8 cols
    int row = w*4 + row4;
    int cb = rlo*8;
    f32x4 va = *(const f32x4*)&aggl[row][cb];
    f32x4 vb = *(const f32x4*)&aggl[row][cb+4];
    float s = va[0]+va[1]+va[2]+va[3] + vb[0]+vb[1]+vb[2]+vb[3];
    #pragma unroll
    for (int st = 1; st < 16; st <<= 1) s += __shfl_xor(s, st, 64);
    float mu = s * (1.f/128.f);
    f32x4 da = va - mu, db = vb - mu;
    float s2 = da[0]*da[0]+da[1]*da[1]+da[2]*da[2]+da[3]*da[3]
             + db[0]*db[0]+db[1]*db[1]+db[2]*db[2]+db[3]*db[3];
    #pragma unroll
    for (int st = 1; st < 16; st <<= 1) s2 += __shfl_xor(s2, st, 64);
    float inv = rsqrtf(s2*(1.f/128.f) + 1e-5f);
    f32x4 ga = *(const f32x4*)&lng[cb], gb = *(const f32x4*)&lng[cb+4];
    f32x4 ba = *(const f32x4*)&lnb[cb], bb = *(const f32x4*)&lnb[cb+4];
    f32x4 za = da*inv*ga + ba, zb = db*inv*gb + bb;
    half8 hz = { (f16)za[0],(f16)za[1],(f16)za[2],(f16)za[3],
                 (f16)zb[0],(f16)zb[1],(f16)zb[2],(f16)zb[3] };
    *(half8*)&zl[row][cb] = hz;
  }
  __syncthreads();
  // ---- MLP single pass: W1 (wave w -> cols w*128..+127), then W2 full-K
  half8 az[4];
  #pragma unroll
  for (int kc = 0; kc < 4; ++kc)
    az[kc] = *(const half8*)&zl[rlo][kc*32 + row4*8];
  #pragma unroll
  for (int ntl = 0; ntl < 8; ++ntl) {
    int nt = w*8 + ntl;
    int col = nt*16 + rlo;
    f32x4 acc = {0.f,0.f,0.f,0.f};
    #pragma unroll
    for (int kc = 0; kc < 4; ++kc) {
      half8 b = *(const half8*)&W1t_l[(size_t)col*128 + kc*32 + row4*8];
      acc = __builtin_amdgcn_mfma_f32_16x16x32_f16(az[kc], b, acc, 0, 0, 0);
    }
    float bias = b1_l[col];
    #pragma unroll
    for (int j = 0; j < 4; ++j)
      y1[row4*4 + j][col] = (f16)gelu_tanh(acc[j] + bias);
  }
  __syncthreads();
  half8 a2[16];
  #pragma unroll
  for (int kc2 = 0; kc2 < 16; ++kc2)
    a2[kc2] = *(const half8*)&y1[rlo][kc2*32 + row4*8];
  f32x4 acc2[2] = {{0.f,0.f,0.f,0.f},{0.f,0.f,0.f,0.f}};
  #pragma unroll
  for (int nt2 = 0; nt2 < 2; ++nt2) {
    int c = (w*2 + nt2)*16 + rlo;
    #pragma unroll
    for (int kc2 = 0; kc2 < 16; ++kc2) {
      half8 b = *(const half8*)&W2t_l[(size_t)c*512 + kc2*32 + row4*8];
      acc2[nt2] = __builtin_amdgcn_mfma_f32_16x16x32_f16(a2[kc2], b, acc2[nt2], 0, 0, 0);
    }
  }
  #pragma unroll
  for (int nt2 = 0; nt2 < 2; ++nt2) {
    int col = (w*2 + nt2)*16 + rlo;
    float bias = b2_l[col];
    #pragma unroll
    for (int j = 0; j < 4; ++j) {
      size_t n = (size_t)(n0 + row4*4 + j);
      hout[n*128 + col] = acc2[nt2][j] + bias + hin[n*128 + col];
    }
  }
}

// ---------------- readout ------------------------------------------------------------
__global__ __launch_bounds__(256) void readout_kernel(const float* __restrict__ h,
    const float* __restrict__ Wr, const float* __restrict__ br, float* __restrict__ out) {
  int n = blockIdx.x*256 + threadIdx.x;
  f32x4 acc = {0.f,0.f,0.f,0.f};
  #pragma unroll
  for (int cb = 0; cb < 32; ++cb) {
    f32x4 hv = *(const f32x4*)(h + (size_t)n*128 + cb*4);
    f32x4 wv = *(const f32x4*)(Wr + cb*4);
    acc += hv*wv;
  }
  out[n] = acc[0]+acc[1]+acc[2]+acc[3] + br[0];
}

extern "C" void kernel_launch(void* const* d_in, const int* in_sizes, int n_in,
                              void* d_out, int out_size, void* d_ws, size_t ws_size,
                              hipStream_t stream) {
  const float* x   = (const float*)d_in[0];
  const float* pos = (const float*)d_in[1];
  const float* We  = (const float*)d_in[3];
  const float* Wb1 = (const float*)d_in[4];
  const float* bb1 = (const float*)d_in[5];
  const float* Wb2 = (const float*)d_in[6];
  const float* bb2 = (const float*)d_in[7];
  const float* Wk  = (const float*)d_in[8];
  const float* lng = (const float*)d_in[9];
  const float* lnb = (const float*)d_in[10];
  const float* W1  = (const float*)d_in[11];
  const float* b1  = (const float*)d_in[12];
  const float* W2  = (const float*)d_in[13];
  const float* b2  = (const float*)d_in[14];
  const float* Wr  = (const float*)d_in[15];
  const float* br  = (const float*)d_in[16];
  float* out = (float*)d_out;

  char* p = (char*)d_ws;
  int*   srci  = (int*)p;     p += (size_t)EE*4;
  float* dedge = (float*)p;   p += (size_t)EE*4;
  f16*   kernA = (f16*)p;     p += (size_t)EE*128*2;
  float* hA    = (float*)p;   p += (size_t)NN*128*4;
  float* hB    = (float*)p;   p += (size_t)NN*128*4;
  f16* Wb2t    = (f16*)p;     p += (size_t)16384*2;
  f16* Wkt     = (f16*)p;     p += (size_t)65536*2;
  f16* W1t     = (f16*)p;     p += (size_t)262144*2;
  f16* W2t     = (f16*)p;     p += (size_t)262144*2;

  prep_kernel<<<2368, 256, 0, stream>>>(Wb2, Wk, W1, W2, Wb2t, Wkt, W1t, W2t);
  knn_kernel<<<NN/4, 256, 0, stream>>>(pos, srci, dedge);
  basis_kernel<<<2048, 256, 0, stream>>>(dedge, Wb1, bb1, Wb2t, bb2, kernA);
  embed_kernel<<<NN/8, 256, 0, stream>>>(x, We, hA);
  float* hin = hA;
  for (int lyr = 0; lyr < NL; ++lyr) {
    float* hout = (hin == hA) ? hB : hA;
    layer_kernel<<<NN/16, 256, 0, stream>>>(kernA, Wkt + lyr*16384, srci, hin,
        lng + lyr*128, lnb + lyr*128,
        W1t + (size_t)lyr*65536, b1 + lyr*512, W2t + (size_t)lyr*65536, b2 + lyr*128, hout);
    hin = hout;
  }
  readout_kernel<<<NN/256, 256, 0, stream>>>(hin, Wr, br, out);
}

// Round 9
// 417.115 us; speedup vs baseline: 3.6019x; 1.0069x over previous
//
#include <hip/hip_runtime.h>
#include <hip/hip_bf16.h>

#define NN 16384
#define GG 2048
#define KNN 16
#define EE (NN*KNN)
#define NL 4

typedef _Float16 f16;
typedef _Float16 half8 __attribute__((ext_vector_type(8)));
typedef _Float16 half4 __attribute__((ext_vector_type(4)));
typedef float f32x4 __attribute__((ext_vector_type(4)));
typedef unsigned long long u64;

// gelu tanh-approx in sigmoid form: x*sigmoid(2y), y=a(x+b x^3)
__device__ __forceinline__ float gelu_tanh(float x) {
  float s = x*x;
  float u = __fmaf_rn(-0.0713548194f, s, -1.5957691216f);   // -2ab*s - 2a
  float p = __expf(x*u);
  return x * __builtin_amdgcn_rcpf(1.0f + p);
}

__device__ __forceinline__ int mbcnt64(u64 m) {
  return __builtin_amdgcn_mbcnt_hi((unsigned)(m >> 32),
         __builtin_amdgcn_mbcnt_lo((unsigned)m, 0));
}

// ---------------- kNN: one WAVE per node -------------------------------------------
// key = (f32bits(d2)<<32)|j : u64 order == (d2 asc, idx asc) == lax.top_k order.
// Scan: 4-deep per-lane sorted list. Select: 42-step ballot binary search for the
// 16th-smallest key (bits 62..32 = d2, 10..0 = idx; keys unique -> exactly 16
// survivors, no tie handling). Survivors scatter to per-wave LDS via mbcnt offsets,
// 16 lanes rank via broadcast reads. Fallback: if any lane's 4th value <= T, its
// dropped 5th might belong -> re-run exact 16-deep (provably lossless) path.
#define INS(kk) { bool sw = key < kk; u64 tmp = kk; kk = sw ? key : kk; key = sw ? tmp : key; }

__global__ __launch_bounds__(256) void knn_kernel(const float* __restrict__ pos,
    int* __restrict__ srci, float* __restrict__ dedge) {
  __shared__ u64 sel[4][16];            // per-wave survivor slots (512 B)
  int tid = threadIdx.x;
  int wv = tid >> 6;
  int node = blockIdx.x*4 + wv;
  int lane = tid & 63;
  int base = node & ~(GG-1);
  float qx = pos[(size_t)node*3+0], qy = pos[(size_t)node*3+1], qz = pos[(size_t)node*3+2];

  u64 ck[4] = {~0ull,~0ull,~0ull,~0ull};
  for (int it = 0; it < 32; ++it) {
    int j = it*64 + lane;
    const float* pr = pos + (size_t)(base+j)*3;
    float dx = __fsub_rn(qx, pr[0]);
    float dy = __fsub_rn(qy, pr[1]);
    float dz = __fsub_rn(qz, pr[2]);
    float d2 = __fadd_rn(__fadd_rn(__fmul_rn(dx,dx), __fmul_rn(dy,dy)), __fmul_rn(dz,dz));
    u64 key = ((u64)__float_as_uint(d2) << 32) | (unsigned)j;
    #pragma unroll
    for (int q = 0; q < 4; ++q) INS(ck[q])
  }
  // binary-search T = 16th-smallest key: max P with #{keys < P} < 16
  u64 T = 0;
  for (int b = 62; b >= 0; --b) {
    if (b == 31) b = 10;                // skip always-zero bits 31..11
    u64 t = T | (1ull << b);
    int cnt = 0;
    #pragma unroll
    for (int q = 0; q < 4; ++q) cnt += __popcll(__ballot(ck[q] < t));
    if (cnt < 16) T = t;
  }
  if (!__any(ck[3] <= T)) {
    // fast path: no lane's list saturated inside top-16 -> 4-deep lists are lossless
    int offb = 0;
    #pragma unroll
    for (int q = 0; q < 4; ++q) {
      u64 m = __ballot(ck[q] <= T);
      if (ck[q] <= T) sel[wv][offb + mbcnt64(m)] = ck[q];
      offb += __popcll(m);
    }
  } else {
    // exact fallback: 16-deep per-lane list (cannot lose; ~1% of waves)
    u64 kf[16];
    #pragma unroll
    for (int q = 0; q < 16; ++q) kf[q] = ~0ull;
    for (int it = 0; it < 32; ++it) {
      int j = it*64 + lane;
      const float* pr = pos + (size_t)(base+j)*3;
      float dx = __fsub_rn(qx, pr[0]);
      float dy = __fsub_rn(qy, pr[1]);
      float dz = __fsub_rn(qz, pr[2]);
      float d2 = __fadd_rn(__fadd_rn(__fmul_rn(dx,dx), __fmul_rn(dy,dy)), __fmul_rn(dz,dz));
      u64 key = ((u64)__float_as_uint(d2) << 32) | (unsigned)j;
      if (key < kf[15]) {
        #pragma unroll
        for (int q = 0; q < 16; ++q) INS(kf[q])
      }
    }
    u64 T2 = 0;
    for (int b = 62; b >= 0; --b) {
      if (b == 31) b = 10;
      u64 t = T2 | (1ull << b);
      int cnt = 0;
      #pragma unroll
      for (int q = 0; q < 16; ++q) cnt += __popcll(__ballot(kf[q] < t));
      if (cnt < 16) T2 = t;
    }
    int offb = 0;
    #pragma unroll
    for (int q = 0; q < 16; ++q) {
      u64 m = __ballot(kf[q] <= T2);
      if (kf[q] <= T2) sel[wv][offb + mbcnt64(m)] = kf[q];
      offb += __popcll(m);
    }
  }
  // rank 16 survivors (broadcast LDS reads; within-wave ordering, no barrier)
  if (lane < KNN) {
    u64 e = sel[wv][lane];
    int rank = 0;
    #pragma unroll
    for (int k2 = 0; k2 < 16; ++k2) rank += (sel[wv][k2] < e) ? 1 : 0;
    int j = (int)(e & 0xffffffffu);
    float d2v = __uint_as_float((unsigned)(e >> 32));
    srci[node*KNN + rank] = base + j;
    dedge[node*KNN + rank] = sqrtf(__fadd_rn(d2v, 1e-12f));
  }
}

// ---------------- weight transpose + f16 convert (transposed [col][k] layouts) -------
__global__ __launch_bounds__(256) void prep_kernel(
    const float* __restrict__ Wb2, const float* __restrict__ Wk,
    const float* __restrict__ W1, const float* __restrict__ W2,
    f16* __restrict__ Wb2t, f16* __restrict__ Wkt,
    f16* __restrict__ W1t, f16* __restrict__ W2t) {
  int i = blockIdx.x*256 + threadIdx.x;
  if (i < 16384) {
    int c = i >> 7, k = i & 127;
    Wb2t[i] = (f16)Wb2[k*128 + c];
    return;
  }
  i -= 16384;
  if (i < 65536) {
    int l = i >> 14, r = i & 16383; int c = r >> 7, k = r & 127;
    Wkt[i] = (f16)Wk[l*16384 + k*128 + c];
    return;
  }
  i -= 65536;
  if (i < 262144) {
    int l = i >> 16, r = i & 65535; int c = r >> 7, k = r & 127;   // c<512,k<128
    W1t[i] = (f16)W1[l*65536 + k*512 + c];
    return;
  }
  i -= 262144;
  if (i < 262144) {
    int l = i >> 16, r = i & 65535; int c = r >> 9, k = r & 511;   // c<128,k<512
    W2t[i] = (f16)W2[l*65536 + k*128 + c];
  }
}

// ---------------- embed: h = x[N,65] @ We[65,128] (f32 VALU) -------------------------
__global__ __launch_bounds__(256) void embed_kernel(const float* __restrict__ x,
    const float* __restrict__ We, float* __restrict__ h) {
  int t = threadIdx.x;
  int n = blockIdx.x*8 + (t >> 5);
  int q = (t & 31) * 4;
  f32x4 acc = {0.f,0.f,0.f,0.f};
  const float* xr = x + n*65;
  for (int k = 0; k < 65; ++k) {
    float xv = xr[k];
    f32x4 wv = *(const f32x4*)(We + k*128 + q);
    acc += xv * wv;
  }
  *(f32x4*)(h + (size_t)n*128 + q) = acc;
}

// ---------------- edge basis v5: Wb2 staged in LDS (kills B-load latency) -----------
__global__ __launch_bounds__(256) void basis_kernel(const float* __restrict__ dedge,
    const float* __restrict__ Wb1, const float* __restrict__ bb1,
    const f16* __restrict__ Wb2t, const float* __restrict__ bb2,
    f16* __restrict__ kernA) {
  __shared__ f16 Wb2s[128][136];  // 34.8KB, padded: B-frag ds_read_b128 2-way max
  __shared__ f16 kb[64][136];     // 17.4KB, rows w*16.. private per wave
  int t = threadIdx.x;
  #pragma unroll
  for (int it = 0; it < 8; ++it) {      // stage Wb2t (32KB) coalesced
    int idx = it*256 + t;
    int row = idx >> 4, k8 = (idx & 15) * 8;
    *(half8*)&Wb2s[row][k8] = *(const half8*)&Wb2t[row*128 + k8];
  }
  __syncthreads();
  int w = t >> 6, l = t & 63;
  int row4 = l >> 4, rlo = l & 15;
  #pragma unroll
  for (int tt = 0; tt < 2; ++tt) {
    size_t Tg = (size_t)blockIdx.x*8 + (size_t)w*2 + tt;
    float d = dedge[Tg*16 + rlo];
    float d2 = d*d, d3 = d2*d;
    half8 a[4];
    #pragma unroll
    for (int kc = 0; kc < 4; ++kc) {
      int k0 = kc*32 + row4*8;
      f32x4 w1a = *(const f32x4*)&Wb1[k0],     w1b = *(const f32x4*)&Wb1[k0+4];
      f32x4 w2a = *(const f32x4*)&Wb1[128+k0], w2b = *(const f32x4*)&Wb1[128+k0+4];
      f32x4 w3a = *(const f32x4*)&Wb1[256+k0], w3b = *(const f32x4*)&Wb1[256+k0+4];
      f32x4 bba = *(const f32x4*)&bb1[k0],     bbb = *(const f32x4*)&bb1[k0+4];
      #pragma unroll
      for (int j = 0; j < 4; ++j) {
        a[kc][j]   = (f16)gelu_tanh(d*w1a[j] + d2*w2a[j] + d3*w3a[j] + bba[j]);
        a[kc][4+j] = (f16)gelu_tanh(d*w1b[j] + d2*w2b[j] + d3*w3b[j] + bbb[j]);
      }
    }
    f32x4 acc[8];
    #pragma unroll
    for (int nt = 0; nt < 8; ++nt) {
      acc[nt] = (f32x4){0.f,0.f,0.f,0.f};
      #pragma unroll
      for (int kc = 0; kc < 4; ++kc) {
        half8 b = *(const half8*)&Wb2s[nt*16 + rlo][kc*32 + row4*8];
        acc[nt] = __builtin_amdgcn_mfma_f32_16x16x32_f16(a[kc], b, acc[nt], 0, 0, 0);
      }
    }
    #pragma unroll
    for (int nt = 0; nt < 8; ++nt) {
      float bias = bb2[nt*16 + rlo];
      #pragma unroll
      for (int j = 0; j < 4; ++j)
        kb[w*16 + row4*4 + j][nt*16 + rlo] = (f16)gelu_tanh(acc[nt][j] + bias);
    }
    // within-wave RAW on LDS: compiler inserts lgkmcnt wait; no barrier needed
    #pragma unroll
    for (int kc = 0; kc < 4; ++kc) {
      half8 v = *(const half8*)&kb[w*16 + rlo][kc*32 + row4*8];
      *(half8*)&kernA[((Tg*4 + kc)*64 + l)*8] = v;
    }
  }
}

// ---------------- fused layer: conv + LN + MLP + residual, 16 nodes/block -----------
__global__ __launch_bounds__(256) void layer_kernel(const f16* __restrict__ kernA,
    const f16* __restrict__ Wkt_l, const int* __restrict__ srci,
    const float* __restrict__ hin,
    const float* __restrict__ lng, const float* __restrict__ lnb,
    const f16* __restrict__ W1t_l, const float* __restrict__ b1_l,
    const f16* __restrict__ W2t_l, const float* __restrict__ b2_l,
    float* __restrict__ hout) {
  __shared__ float aggl[16][132];   // 8.4KB  conv output (node-local rows)
  __shared__ f16 zl[16][136];       // 4.4KB  LN output
  __shared__ f16 y1[16][520];       // 16.6KB full y1
  int t = threadIdx.x;
  int w = t >> 6, l = t & 63;
  int row4 = l >> 4, rlo = l & 15;
  int n0 = blockIdx.x * 16;

  // ---- conv: wave w -> nodes n0 + w*4 .. +3; two nt-halves to bound VGPR use
  #pragma unroll
  for (int hh = 0; hh < 2; ++hh) {
    half8 bf[4][4];
    #pragma unroll
    for (int nt4 = 0; nt4 < 4; ++nt4)
      #pragma unroll
      for (int kc = 0; kc < 4; ++kc)
        bf[nt4][kc] = *(const half8*)&Wkt_l[((hh*4 + nt4)*16 + rlo)*128 + kc*32 + row4*8];
    #pragma unroll
    for (int m = 0; m < 4; ++m) {
      int node = n0 + w*4 + m;
      half8 a[4];
      #pragma unroll
      for (int kc = 0; kc < 4; ++kc)
        a[kc] = *(const half8*)&kernA[(((size_t)node*4 + kc)*64 + l)*8];
      int sidx[4];
      #pragma unroll
      for (int j = 0; j < 4; ++j)
        sidx[j] = srci[node*16 + row4*4 + j];
      #pragma unroll
      for (int nt4 = 0; nt4 < 4; ++nt4) {
        f32x4 acc = {0.f,0.f,0.f,0.f};
        #pragma unroll
        for (int kc = 0; kc < 4; ++kc)
          acc = __builtin_amdgcn_mfma_f32_16x16x32_f16(a[kc], bf[nt4][kc], acc, 0, 0, 0);
        int col = (hh*4 + nt4)*16 + rlo;
        float p = 0.f;
        #pragma unroll
        for (int j = 0; j < 4; ++j)
          p += acc[j] * hin[(size_t)sidx[j]*128 + col];
        p += __shfl_xor(p, 16, 64);
        p += __shfl_xor(p, 32, 64);
        if (l < 16) aggl[w*4 + m][(hh*4 + nt4)*16 + l] = p;
      }
    }
  }
  __syncthreads();
  { // ---- LayerNorm: 16 lanes per row; row = w*4 + row4, lane rlo owns 8 cols
    int row = w*4 + row4;
    int cb = rlo*8;
    f32x4 va = *(const f32x4*)&aggl[row][cb];
    f32x4 vb = *(const f32x4*)&aggl[row][cb+4];
    float s = va[0]+va[1]+va[2]+va[3] + vb[0]+vb[1]+vb[2]+vb[3];
    #pragma unroll
    for (int st = 1; st < 16; st <<= 1) s += __shfl_xor(s, st, 64);
    float mu = s * (1.f/128.f);
    f32x4 da = va - mu, db = vb - mu;
    float s2 = da[0]*da[0]+da[1]*da[1]+da[2]*da[2]+da[3]*da[3]
             + db[0]*db[0]+db[1]*db[1]+db[2]*db[2]+db[3]*db[3];
    #pragma unroll
    for (int st = 1; st < 16; st <<= 1) s2 += __shfl_xor(s2, st, 64);
    float inv = rsqrtf(s2*(1.f/128.f) + 1e-5f);
    f32x4 ga = *(const f32x4*)&lng[cb], gb = *(const f32x4*)&lng[cb+4];
    f32x4 ba = *(const f32x4*)&lnb[cb], bb = *(const f32x4*)&lnb[cb+4];
    f32x4 za = da*inv*ga + ba, zb = db*inv*gb + bb;
    half8 hz = { (f16)za[0],(f16)za[1],(f16)za[2],(f16)za[3],
                 (f16)zb[0],(f16)zb[1],(f16)zb[2],(f16)zb[3] };
    *(half8*)&zl[row][cb] = hz;
  }
  __syncthreads();
  // ---- MLP single pass: W1 (wave w -> cols w*128..+127), then W2 full-K
  half8 az[4];
  #pragma unroll
  for (int kc = 0; kc < 4; ++kc)
    az[kc] = *(const half8*)&zl[rlo][kc*32 + row4*8];
  #pragma unroll
  for (int ntl = 0; ntl < 8; ++ntl) {
    int nt = w*8 + ntl;
    int col = nt*16 + rlo;
    f32x4 acc = {0.f,0.f,0.f,0.f};
    #pragma unroll
    for (int kc = 0; kc < 4; ++kc) {
      half8 b = *(const half8*)&W1t_l[(size_t)col*128 + kc*32 + row4*8];
      acc = __builtin_amdgcn_mfma_f32_16x16x32_f16(az[kc], b, acc, 0, 0, 0);
    }
    float bias = b1_l[col];
    #pragma unroll
    for (int j = 0; j < 4; ++j)
      y1[row4*4 + j][col] = (f16)gelu_tanh(acc[j] + bias);
  }
  __syncthreads();
  half8 a2[16];
  #pragma unroll
  for (int kc2 = 0; kc2 < 16; ++kc2)
    a2[kc2] = *(const half8*)&y1[rlo][kc2*32 + row4*8];
  f32x4 acc2[2] = {{0.f,0.f,0.f,0.f},{0.f,0.f,0.f,0.f}};
  #pragma unroll
  for (int nt2 = 0; nt2 < 2; ++nt2) {
    int c = (w*2 + nt2)*16 + rlo;
    #pragma unroll
    for (int kc2 = 0; kc2 < 16; ++kc2) {
      half8 b = *(const half8*)&W2t_l[(size_t)c*512 + kc2*32 + row4*8];
      acc2[nt2] = __builtin_amdgcn_mfma_f32_16x16x32_f16(a2[kc2], b, acc2[nt2], 0, 0, 0);
    }
  }
  #pragma unroll
  for (int nt2 = 0; nt2 < 2; ++nt2) {
    int col = (w*2 + nt2)*16 + rlo;
    float bias = b2_l[col];
    #pragma unroll
    for (int j = 0; j < 4; ++j) {
      size_t n = (size_t)(n0 + row4*4 + j);
      hout[n*128 + col] = acc2[nt2][j] + bias + hin[n*128 + col];
    }
  }
}

// ---------------- readout ------------------------------------------------------------
__global__ __launch_bounds__(256) void readout_kernel(const float* __restrict__ h,
    const float* __restrict__ Wr, const float* __restrict__ br, float* __restrict__ out) {
  int n = blockIdx.x*256 + threadIdx.x;
  f32x4 acc = {0.f,0.f,0.f,0.f};
  #pragma unroll
  for (int cb = 0; cb < 32; ++cb) {
    f32x4 hv = *(const f32x4*)(h + (size_t)n*128 + cb*4);
    f32x4 wv = *(const f32x4*)(Wr + cb*4);
    acc += hv*wv;
  }
  out[n] = acc[0]+acc[1]+acc[2]+acc[3] + br[0];
}

extern "C" void kernel_launch(void* const* d_in, const int* in_sizes, int n_in,
                              void* d_out, int out_size, void* d_ws, size_t ws_size,
                              hipStream_t stream) {
  const float* x   = (const float*)d_in[0];
  const float* pos = (const float*)d_in[1];
  const float* We  = (const float*)d_in[3];
  const float* Wb1 = (const float*)d_in[4];
  const float* bb1 = (const float*)d_in[5];
  const float* Wb2 = (const float*)d_in[6];
  const float* bb2 = (const float*)d_in[7];
  const float* Wk  = (const float*)d_in[8];
  const float* lng = (const float*)d_in[9];
  const float* lnb = (const float*)d_in[10];
  const float* W1  = (const float*)d_in[11];
  const float* b1  = (const float*)d_in[12];
  const float* W2  = (const float*)d_in[13];
  const float* b2  = (const float*)d_in[14];
  const float* Wr  = (const float*)d_in[15];
  const float* br  = (const float*)d_in[16];
  float* out = (float*)d_out;

  char* p = (char*)d_ws;
  int*   srci  = (int*)p;     p += (size_t)EE*4;
  float* dedge = (float*)p;   p += (size_t)EE*4;
  f16*   kernA = (f16*)p;     p += (size_t)EE*128*2;
  float* hA    = (float*)p;   p += (size_t)NN*128*4;
  float* hB    = (float*)p;   p += (size_t)NN*128*4;
  f16* Wb2t    = (f16*)p;     p += (size_t)16384*2;
  f16* Wkt     = (f16*)p;     p += (size_t)65536*2;
  f16* W1t     = (f16*)p;     p += (size_t)262144*2;
  f16* W2t     = (f16*)p;     p += (size_t)262144*2;

  prep_kernel<<<2368, 256, 0, stream>>>(Wb2, Wk, W1, W2, Wb2t, Wkt, W1t, W2t);
  knn_kernel<<<NN/4, 256, 0, stream>>>(pos, srci, dedge);
  basis_kernel<<<2048, 256, 0, stream>>>(dedge, Wb1, bb1, Wb2t, bb2, kernA);
  embed_kernel<<<NN/8, 256, 0, stream>>>(x, We, hA);
  float* hin = hA;
  for (int lyr = 0; lyr < NL; ++lyr) {
    float* hout = (hin == hA) ? hB : hA;
    layer_kernel<<<NN/16, 256, 0, stream>>>(kernA, Wkt + lyr*16384, srci, hin,
        lng + lyr*128, lnb + lyr*128,
        W1t + (size_t)lyr*65536, b1 + lyr*512, W2t + (size_t)lyr*65536, b2 + lyr*128, hout);
    hin = hout;
  }
  readout_kernel<<<NN/256, 256, 0, stream>>>(hin, Wr, br, out);
}